// Round 5
// baseline (333.759 us; speedup 1.0000x reference)
//
#include <hip/hip_runtime.h>
#include <hip/hip_fp16.h>

constexpr int DIN = 32;
constexpr int DH  = 64;
constexpr int NBSHIFT = 8;            // 256 nodes per coarse bucket
constexpr int TILE_A  = 16384;        // edges per phase-A block

// ===================== CSR build =====================

__global__ __launch_bounds__(256) void k_hist(
    const int* __restrict__ dst, int* __restrict__ deg, int E) {
  int e = blockIdx.x * 256 + threadIdx.x;
  if (e >= E) return;
  atomicAdd(&deg[dst[e]], 1);
}

__global__ __launch_bounds__(256) void k_scan1(
    const int* __restrict__ deg, int* __restrict__ ex,
    int* __restrict__ bsum, int n) {
  __shared__ int ts[256];
  int base = blockIdx.x * 1024 + threadIdx.x * 4;
  int v[4];
  int s = 0;
#pragma unroll
  for (int q = 0; q < 4; ++q) {
    int idx = base + q;
    v[q] = (idx < n) ? deg[idx] : 0;
    s += v[q];
  }
  ts[threadIdx.x] = s;
  __syncthreads();
  for (int off = 1; off < 256; off <<= 1) {
    int val = (threadIdx.x >= off) ? ts[threadIdx.x - off] : 0;
    __syncthreads();
    ts[threadIdx.x] += val;
    __syncthreads();
  }
  int run = ts[threadIdx.x] - s;
#pragma unroll
  for (int q = 0; q < 4; ++q) {
    int idx = base + q;
    if (idx < n) ex[idx] = run;
    run += v[q];
  }
  if (threadIdx.x == 255) bsum[blockIdx.x] = ts[255];
}

__global__ __launch_bounds__(256) void k_scan2(int* __restrict__ bsum, int nb) {
  __shared__ int ts[256];
  int v = (threadIdx.x < nb) ? bsum[threadIdx.x] : 0;
  ts[threadIdx.x] = v;
  __syncthreads();
  for (int off = 1; off < 256; off <<= 1) {
    int val = (threadIdx.x >= off) ? ts[threadIdx.x - off] : 0;
    __syncthreads();
    ts[threadIdx.x] += val;
    __syncthreads();
  }
  if (threadIdx.x < nb) bsum[threadIdx.x] = ts[threadIdx.x] - v;
}

// finalize rp; also initialize coarse-bucket cursors bcur[b] = rp[b*256]
__global__ __launch_bounds__(256) void k_scan3(
    int* __restrict__ rp, const int* __restrict__ bsum,
    int* __restrict__ bcur, int n, int E) {
  int i = blockIdx.x * 256 + threadIdx.x;
  if (i > n) return;
  if (i == n) { rp[n] = E; return; }
  int val = rp[i] + bsum[i >> 10];
  rp[i] = val;
  if ((i & 255) == 0) bcur[i >> NBSHIFT] = val;
}

// Phase A: bin edges into coarse dst-buckets, packed as (dst&255)<<17 | src.
// Requires n < 2^17 (n = 100000 here).
__global__ __launch_bounds__(256) void k_binA(
    const int* __restrict__ src, const int* __restrict__ dst,
    int* __restrict__ bcur, unsigned* __restrict__ bin,
    int E, int nbuckets) {
  __shared__ int hist[512];
  __shared__ int base[512];
  long long t0 = (long long)blockIdx.x * TILE_A;
  int cnt = (int)min((long long)TILE_A, (long long)E - t0);
  for (int i = threadIdx.x; i < nbuckets; i += 256) hist[i] = 0;
  __syncthreads();
  for (int r = threadIdx.x; r < cnt; r += 256)
    atomicAdd(&hist[dst[t0 + r] >> NBSHIFT], 1);
  __syncthreads();
  for (int i = threadIdx.x; i < nbuckets; i += 256) {
    int c = hist[i];
    base[i] = c ? atomicAdd(&bcur[i], c) : 0;
    hist[i] = 0;                       // reuse as local cursor
  }
  __syncthreads();
  for (int r = threadIdx.x; r < cnt; r += 256) {
    int d = dst[t0 + r];
    int s = src[t0 + r];
    int b = d >> NBSHIFT;
    int off = atomicAdd(&hist[b], 1);
    bin[base[b] + off] = ((unsigned)(d & 255) << 17) | (unsigned)s;
  }
}

// Phase B: exact counting sort inside each bucket
__global__ __launch_bounds__(256) void k_fillB(
    const unsigned* __restrict__ bin, const int* __restrict__ rp,
    int* __restrict__ ssrc, int n) {
  __shared__ int cur[256];
  int nbase = blockIdx.x << NBSHIFT;
  int nend = min(nbase + 256, n);
  int nn = nend - nbase;
  if (threadIdx.x < nn) cur[threadIdx.x] = rp[nbase + threadIdx.x];
  __syncthreads();
  int ebeg = rp[nbase];
  int eend = rp[nend];
  for (int e = ebeg + (int)threadIdx.x; e < eend; e += 256) {
    unsigned u = bin[e];
    int dlow = (int)(u >> 17);
    int s = (int)(u & 0x1FFFF);
    int pos = atomicAdd(&cur[dlow], 1);
    ssrc[pos] = s;
  }
}

// ===================== fp32 -> fp16 conversion =====================

__global__ __launch_bounds__(256) void k_tohalf(
    const float2* __restrict__ in, __half2* __restrict__ out, int n2) {
  int i = blockIdx.x * 256 + threadIdx.x;
  if (i >= n2) return;
  float2 v = in[i];
  out[i] = __floats2half2_rn(v.x, v.y);
}

// ===================== gather-based segment sums (fp16 features) ============

// g = 1<<LOGG lanes per node, each lane covers 2 features (half2). D = 2*g.
template<int LOGG>
__global__ __launch_bounds__(256) void k_gather_h(
    const __half2* __restrict__ feat, const int* __restrict__ rp,
    const int* __restrict__ ssrc, float2* __restrict__ agg, int n) {
  int t = blockIdx.x * 256 + threadIdx.x;
  int node = t >> LOGG;
  int f2 = t & ((1 << LOGG) - 1);
  if (node >= n) return;
  int beg = rp[node], end = rp[node + 1];
  float ax = 0.f, ay = 0.f;
  int e = beg;
  for (; e + 3 < end; e += 4) {
    int s0 = ssrc[e];
    int s1 = ssrc[e + 1];
    int s2 = ssrc[e + 2];
    int s3 = ssrc[e + 3];
    float2 v0 = __half22float2(feat[((size_t)s0 << LOGG) + f2]);
    float2 v1 = __half22float2(feat[((size_t)s1 << LOGG) + f2]);
    float2 v2 = __half22float2(feat[((size_t)s2 << LOGG) + f2]);
    float2 v3 = __half22float2(feat[((size_t)s3 << LOGG) + f2]);
    ax += v0.x; ay += v0.y;
    ax += v1.x; ay += v1.y;
    ax += v2.x; ay += v2.y;
    ax += v3.x; ay += v3.y;
  }
  for (; e < end; ++e) {
    float2 v = __half22float2(feat[((size_t)ssrc[e] << LOGG) + f2]);
    ax += v.x; ay += v.y;
  }
  agg[((size_t)node << LOGG) + f2] = make_float2(ax, ay);
}

// ===================== dense layers =====================

union U16 { uint4 u; __half2 h[4]; };

// h1 = relu(agg@w1_rel + b1 + x@w1_root), emitted as fp16
// (256,1): allow full registerization of the 64-float input state — no scratch
__global__ __launch_bounds__(256, 1) void layer1_kernel(
    const float* __restrict__ x, const float* __restrict__ agg,
    const float* __restrict__ w_rel, const float* __restrict__ b,
    const float* __restrict__ w_root, __half2* __restrict__ h1h, int n) {
  __shared__ float swr[DH * DIN];   // [j][k], written linearly
  __shared__ float swo[DH * DIN];
  __shared__ float sb[DH];
  for (int idx = threadIdx.x; idx < DIN * DH; idx += blockDim.x) {
    int j = idx / DIN, k = idx % DIN;
    swr[idx] = w_rel[k * DH + j];
    swo[idx] = w_root[k * DH + j];
  }
  if (threadIdx.x < DH) sb[threadIdx.x] = b[threadIdx.x];
  __syncthreads();
  int i = blockIdx.x * blockDim.x + threadIdx.x;
  if (i >= n) return;
  float xr[DIN], ar[DIN];
  const float4* xp = (const float4*)(x + (size_t)i * DIN);
  const float4* ap = (const float4*)(agg + (size_t)i * DIN);
#pragma unroll
  for (int q = 0; q < DIN / 4; ++q) {
    float4 v = xp[q];
    xr[q*4+0] = v.x; xr[q*4+1] = v.y; xr[q*4+2] = v.z; xr[q*4+3] = v.w;
    float4 a = ap[q];
    ar[q*4+0] = a.x; ar[q*4+1] = a.y; ar[q*4+2] = a.z; ar[q*4+3] = a.w;
  }
  for (int j = 0; j < DH; j += 2) {
    float acc0 = sb[j], acc1 = sb[j + 1];
#pragma unroll
    for (int k = 0; k < DIN; ++k) {
      acc0 = fmaf(ar[k], swr[j*DIN+k],     fmaf(xr[k], swo[j*DIN+k],     acc0));
      acc1 = fmaf(ar[k], swr[(j+1)*DIN+k], fmaf(xr[k], swo[(j+1)*DIN+k], acc1));
    }
    h1h[(size_t)i * (DH/2) + (j >> 1)] =
        __floats2half2_rn(fmaxf(acc0, 0.f), fmaxf(acc1, 0.f));
  }
}

// h2 = relu(agg@w2_rel + b2 + h1@w2_root); s = h2@w3_rel  (h1 is fp16)
// (256,1): the 128-float hr/ar state MUST registerize (VGPR 84 -> ~200);
// previous build spilled to scratch -> 245 MB HBM writes, 80 us.
__global__ __launch_bounds__(256, 1) void layer2_kernel(
    const __half2* __restrict__ h1h, const float* __restrict__ agg,
    const float* __restrict__ w_rel, const float* __restrict__ b,
    const float* __restrict__ w_root, const float* __restrict__ w3_rel,
    float* __restrict__ h2, float* __restrict__ s_out, int n) {
  __shared__ float swr[DH * DH];    // [j][k], linear writes
  __shared__ float swo[DH * DH];
  __shared__ float sb[DH];
  __shared__ float sw3[DH];
  for (int idx = threadIdx.x; idx < DH * DH; idx += blockDim.x) {
    int j = idx / DH, k = idx % DH;
    swr[idx] = w_rel[k * DH + j];
    swo[idx] = w_root[k * DH + j];
  }
  if (threadIdx.x < DH) {
    sb[threadIdx.x]  = b[threadIdx.x];
    sw3[threadIdx.x] = w3_rel[threadIdx.x];
  }
  __syncthreads();
  int i = blockIdx.x * blockDim.x + threadIdx.x;
  if (i >= n) return;
  float hr[DH], ar[DH];
  const uint4* hp = (const uint4*)(h1h + (size_t)i * (DH/2));
#pragma unroll
  for (int q = 0; q < DH / 8; ++q) {
    U16 u; u.u = hp[q];
#pragma unroll
    for (int c = 0; c < 4; ++c) {
      float2 v = __half22float2(u.h[c]);
      hr[q*8 + 2*c]     = v.x;
      hr[q*8 + 2*c + 1] = v.y;
    }
  }
  const float4* ap = (const float4*)(agg + (size_t)i * DH);
#pragma unroll
  for (int q = 0; q < DH / 4; ++q) {
    float4 a = ap[q];
    ar[q*4+0] = a.x; ar[q*4+1] = a.y; ar[q*4+2] = a.z; ar[q*4+3] = a.w;
  }
  float sdot = 0.f;
  for (int j = 0; j < DH; ++j) {
    float acc = sb[j];
#pragma unroll
    for (int k = 0; k < DH; ++k)
      acc = fmaf(ar[k], swr[j*DH+k], fmaf(hr[k], swo[j*DH+k], acc));
    float r = fmaxf(acc, 0.f);
    h2[(size_t)i * DH + j] = r;
    sdot = fmaf(r, sw3[j], sdot);
  }
  s_out[i] = sdot;
}

// fused: out = segsum(sv) + b3 + h2@w3_root
__global__ __launch_bounds__(256) void k_final(
    const float* __restrict__ sv, const int* __restrict__ rp,
    const int* __restrict__ ssrc, const float* __restrict__ h2,
    const float* __restrict__ w3_root, const float* __restrict__ b3,
    float* __restrict__ out, int n) {
  __shared__ float sw[DH];
  if (threadIdx.x < DH) sw[threadIdx.x] = w3_root[threadIdx.x];
  __syncthreads();
  int i = blockIdx.x * 256 + threadIdx.x;
  if (i >= n) return;
  int beg = rp[i], end = rp[i + 1];
  float a = b3[0];
  int e = beg;
  for (; e + 3 < end; e += 4) {
    float v0 = sv[ssrc[e]];
    float v1 = sv[ssrc[e + 1]];
    float v2 = sv[ssrc[e + 2]];
    float v3 = sv[ssrc[e + 3]];
    a += v0; a += v1; a += v2; a += v3;
  }
  for (; e < end; ++e) a += sv[ssrc[e]];
  const float4* hp = (const float4*)(h2 + (size_t)i * DH);
#pragma unroll
  for (int q = 0; q < DH / 4; ++q) {
    float4 v = hp[q];
    a = fmaf(v.x, sw[q*4+0], a);
    a = fmaf(v.y, sw[q*4+1], a);
    a = fmaf(v.z, sw[q*4+2], a);
    a = fmaf(v.w, sw[q*4+3], a);
  }
  out[i] = a;
}

// ===================== launch =====================

extern "C" void kernel_launch(void* const* d_in, const int* in_sizes, int n_in,
                              void* d_out, int out_size, void* d_ws, size_t ws_size,
                              hipStream_t stream) {
  const float* x       = (const float*)d_in[0];
  const float* w1_rel  = (const float*)d_in[1];
  const float* b1      = (const float*)d_in[2];
  const float* w1_root = (const float*)d_in[3];
  const float* w2_rel  = (const float*)d_in[4];
  const float* b2      = (const float*)d_in[5];
  const float* w2_root = (const float*)d_in[6];
  const float* w3_rel  = (const float*)d_in[7];
  const float* b3      = (const float*)d_in[8];
  const float* w3_root = (const float*)d_in[9];
  const int*   edge    = (const int*)d_in[10];

  const int n = in_sizes[0] / DIN;        // 100000 (< 2^17 required by packing)
  const int E = in_sizes[10] / 2;         // 1600000
  const int* src = edge;
  const int* dst = edge + E;

  const size_t n64 = (size_t)n * DH;
  float*   AGG  = (float*)d_ws;                 // n*64 f32 (layer1 uses n*32)
  float*   H2   = AGG + n64;                    // n*64 f32
  __half2* H1h  = (__half2*)(H2 + n64);         // n*32 half2
  __half2* XH   = H1h + (size_t)n * (DH/2);     // n*16 half2
  float*   S    = (float*)(XH + (size_t)n * (DIN/2)); // n
  float*   SACC = S + n;                        // n (unused, layout keeper)
  int* RP   = (int*)(SACC + n);                 // n+1
  int* CUR  = RP + (n + 1);                     // n (degree buffer)
  int* SSRC = CUR + n;                          // E
  int* BSUM = SSRC + E;                         // <=256
  int* BCUR = BSUM + 256;                       // <=512 coarse-bucket cursors
  unsigned* BIN = (unsigned*)H2;                // E (dead before layer2 writes H2)

  const int B = 256;
  const int gn = (n + B - 1) / B;
  const int gE = (E + B - 1) / B;
  const int nb = (n + 1023) / 1024;
  const int nbuckets = (n + 255) >> NBSHIFT;    // 391
  const int gA = (E + TILE_A - 1) / TILE_A;     // 98

  // ---- CSR build (two-level counting sort by dst) ----
  hipMemsetAsync(CUR, 0, (size_t)n * sizeof(int), stream);
  k_hist<<<gE, B, 0, stream>>>(dst, CUR, E);
  k_scan1<<<nb, B, 0, stream>>>(CUR, RP, BSUM, n);
  k_scan2<<<1, B, 0, stream>>>(BSUM, nb);
  k_scan3<<<(n + 1 + B - 1) / B, B, 0, stream>>>(RP, BSUM, BCUR, n, E);
  k_binA<<<gA, B, 0, stream>>>(src, dst, BCUR, BIN, E, nbuckets);
  k_fillB<<<nbuckets, B, 0, stream>>>(BIN, RP, SSRC, n);

  // ---- x -> fp16 ----
  {
    int n2 = n * (DIN / 2);
    k_tohalf<<<(n2 + B - 1) / B, B, 0, stream>>>((const float2*)x, XH, n2);
  }

  // ---- layer 1 ----  (16 lanes/node, 32 features)
  {
    long long tot = (long long)n * (DIN / 2);
    k_gather_h<4><<<(unsigned)((tot + B - 1) / B), B, 0, stream>>>(
        XH, RP, SSRC, (float2*)AGG, n);
  }
  layer1_kernel<<<gn, B, 0, stream>>>(x, AGG, w1_rel, b1, w1_root, H1h, n);

  // ---- layer 2 ----  (32 lanes/node, 64 features)
  {
    long long tot = (long long)n * (DH / 2);
    k_gather_h<5><<<(unsigned)((tot + B - 1) / B), B, 0, stream>>>(
        H1h, RP, SSRC, (float2*)AGG, n);
  }
  layer2_kernel<<<gn, B, 0, stream>>>(H1h, AGG, w2_rel, b2, w2_root, w3_rel, H2, S, n);

  // ---- layer 3 (pre-projected by w3_rel in layer2_kernel) ----
  k_final<<<gn, B, 0, stream>>>(S, RP, SSRC, H2, w3_root, b3, (float*)d_out, n);
}

// Round 6
// 272.908 us; speedup vs baseline: 1.2230x; 1.2230x over previous
//
#include <hip/hip_runtime.h>
#include <hip/hip_fp16.h>

typedef _Float16 f16x8 __attribute__((ext_vector_type(8)));
typedef float    f32x4 __attribute__((ext_vector_type(4)));

constexpr int DIN = 32;
constexpr int DH  = 64;
constexpr int NBSHIFT = 8;            // 256 nodes per coarse bucket
constexpr int TILE_A  = 16384;        // edges per phase-A block

// ===================== CSR build =====================

__global__ __launch_bounds__(256) void k_hist(
    const int* __restrict__ dst, int* __restrict__ deg, int E) {
  int e = blockIdx.x * 256 + threadIdx.x;
  if (e >= E) return;
  atomicAdd(&deg[dst[e]], 1);
}

__global__ __launch_bounds__(256) void k_scan1(
    const int* __restrict__ deg, int* __restrict__ ex,
    int* __restrict__ bsum, int n) {
  __shared__ int ts[256];
  int base = blockIdx.x * 1024 + threadIdx.x * 4;
  int v[4];
  int s = 0;
#pragma unroll
  for (int q = 0; q < 4; ++q) {
    int idx = base + q;
    v[q] = (idx < n) ? deg[idx] : 0;
    s += v[q];
  }
  ts[threadIdx.x] = s;
  __syncthreads();
  for (int off = 1; off < 256; off <<= 1) {
    int val = (threadIdx.x >= off) ? ts[threadIdx.x - off] : 0;
    __syncthreads();
    ts[threadIdx.x] += val;
    __syncthreads();
  }
  int run = ts[threadIdx.x] - s;
#pragma unroll
  for (int q = 0; q < 4; ++q) {
    int idx = base + q;
    if (idx < n) ex[idx] = run;
    run += v[q];
  }
  if (threadIdx.x == 255) bsum[blockIdx.x] = ts[255];
}

__global__ __launch_bounds__(256) void k_scan2(int* __restrict__ bsum, int nb) {
  __shared__ int ts[256];
  int v = (threadIdx.x < nb) ? bsum[threadIdx.x] : 0;
  ts[threadIdx.x] = v;
  __syncthreads();
  for (int off = 1; off < 256; off <<= 1) {
    int val = (threadIdx.x >= off) ? ts[threadIdx.x - off] : 0;
    __syncthreads();
    ts[threadIdx.x] += val;
    __syncthreads();
  }
  if (threadIdx.x < nb) bsum[threadIdx.x] = ts[threadIdx.x] - v;
}

__global__ __launch_bounds__(256) void k_scan3(
    int* __restrict__ rp, const int* __restrict__ bsum,
    int* __restrict__ bcur, int n, int E) {
  int i = blockIdx.x * 256 + threadIdx.x;
  if (i > n) return;
  if (i == n) { rp[n] = E; return; }
  int val = rp[i] + bsum[i >> 10];
  rp[i] = val;
  if ((i & 255) == 0) bcur[i >> NBSHIFT] = val;
}

__global__ __launch_bounds__(256) void k_binA(
    const int* __restrict__ src, const int* __restrict__ dst,
    int* __restrict__ bcur, unsigned* __restrict__ bin,
    int E, int nbuckets) {
  __shared__ int hist[512];
  __shared__ int base[512];
  long long t0 = (long long)blockIdx.x * TILE_A;
  int cnt = (int)min((long long)TILE_A, (long long)E - t0);
  for (int i = threadIdx.x; i < nbuckets; i += 256) hist[i] = 0;
  __syncthreads();
  for (int r = threadIdx.x; r < cnt; r += 256)
    atomicAdd(&hist[dst[t0 + r] >> NBSHIFT], 1);
  __syncthreads();
  for (int i = threadIdx.x; i < nbuckets; i += 256) {
    int c = hist[i];
    base[i] = c ? atomicAdd(&bcur[i], c) : 0;
    hist[i] = 0;
  }
  __syncthreads();
  for (int r = threadIdx.x; r < cnt; r += 256) {
    int d = dst[t0 + r];
    int s = src[t0 + r];
    int b = d >> NBSHIFT;
    int off = atomicAdd(&hist[b], 1);
    bin[base[b] + off] = ((unsigned)(d & 255) << 17) | (unsigned)s;
  }
}

__global__ __launch_bounds__(256) void k_fillB(
    const unsigned* __restrict__ bin, const int* __restrict__ rp,
    int* __restrict__ ssrc, int n) {
  __shared__ int cur[256];
  int nbase = blockIdx.x << NBSHIFT;
  int nend = min(nbase + 256, n);
  int nn = nend - nbase;
  if (threadIdx.x < nn) cur[threadIdx.x] = rp[nbase + threadIdx.x];
  __syncthreads();
  int ebeg = rp[nbase];
  int eend = rp[nend];
  for (int e = ebeg + (int)threadIdx.x; e < eend; e += 256) {
    unsigned u = bin[e];
    int dlow = (int)(u >> 17);
    int s = (int)(u & 0x1FFFF);
    int pos = atomicAdd(&cur[dlow], 1);
    ssrc[pos] = s;
  }
}

// ===================== fp32 -> fp16 =====================

__global__ __launch_bounds__(256) void k_tohalf(
    const float2* __restrict__ in, __half2* __restrict__ out, int n2) {
  int i = blockIdx.x * 256 + threadIdx.x;
  if (i >= n2) return;
  float2 v = in[i];
  out[i] = __floats2half2_rn(v.x, v.y);
}

// ===================== gather segment sums =====================
// 1<<LOGG half2-lanes per node; feat rows are LDH2 half2 wide, read at OFFR.
// OUTH: write half2 at row stride LDH2, offset OFFW; else float2 contiguous.
template<int LOGG, int LDH2, int OFFR, int OFFW, bool OUTH>
__global__ __launch_bounds__(256) void k_gather(
    const __half2* __restrict__ feat, const int* __restrict__ rp,
    const int* __restrict__ ssrc, void* __restrict__ outp, int n) {
  int t = blockIdx.x * 256 + threadIdx.x;
  int node = t >> LOGG;
  int f2 = t & ((1 << LOGG) - 1);
  if (node >= n) return;
  int beg = rp[node], end = rp[node + 1];
  float ax = 0.f, ay = 0.f;
  int e = beg;
  for (; e + 3 < end; e += 4) {
    int s0 = ssrc[e];
    int s1 = ssrc[e + 1];
    int s2 = ssrc[e + 2];
    int s3 = ssrc[e + 3];
    float2 v0 = __half22float2(feat[(size_t)s0 * LDH2 + OFFR + f2]);
    float2 v1 = __half22float2(feat[(size_t)s1 * LDH2 + OFFR + f2]);
    float2 v2 = __half22float2(feat[(size_t)s2 * LDH2 + OFFR + f2]);
    float2 v3 = __half22float2(feat[(size_t)s3 * LDH2 + OFFR + f2]);
    ax += v0.x; ay += v0.y;
    ax += v1.x; ay += v1.y;
    ax += v2.x; ay += v2.y;
    ax += v3.x; ay += v3.y;
  }
  for (; e < end; ++e) {
    float2 v = __half22float2(feat[(size_t)ssrc[e] * LDH2 + OFFR + f2]);
    ax += v.x; ay += v.y;
  }
  if (OUTH) {
    ((__half2*)outp)[(size_t)node * LDH2 + OFFW + f2] = __floats2half2_rn(ax, ay);
  } else {
    ((float2*)outp)[((size_t)node << LOGG) + f2] = make_float2(ax, ay);
  }
}

// ===================== layer 1 (VALU) =====================
// h1 = relu(agg@w1_rel + b1 + x@w1_root) -> fp16 into F2[node][64..127]

__global__ __launch_bounds__(256) void layer1_kernel(
    const float* __restrict__ x, const float* __restrict__ agg,
    const float* __restrict__ w_rel, const float* __restrict__ b,
    const float* __restrict__ w_root, __half2* __restrict__ f2h, int n) {
  __shared__ float swr[DH * DIN];   // [j][k], linear writes
  __shared__ float swo[DH * DIN];
  __shared__ float sb[DH];
  for (int idx = threadIdx.x; idx < DIN * DH; idx += blockDim.x) {
    int j = idx / DIN, k = idx % DIN;
    swr[idx] = w_rel[k * DH + j];
    swo[idx] = w_root[k * DH + j];
  }
  if (threadIdx.x < DH) sb[threadIdx.x] = b[threadIdx.x];
  __syncthreads();
  int i = blockIdx.x * blockDim.x + threadIdx.x;
  if (i >= n) return;
  float xr[DIN], ar[DIN];
  const float4* xp = (const float4*)(x + (size_t)i * DIN);
  const float4* ap = (const float4*)(agg + (size_t)i * DIN);
#pragma unroll
  for (int q = 0; q < DIN / 4; ++q) {
    float4 v = xp[q];
    xr[q*4+0] = v.x; xr[q*4+1] = v.y; xr[q*4+2] = v.z; xr[q*4+3] = v.w;
    float4 a = ap[q];
    ar[q*4+0] = a.x; ar[q*4+1] = a.y; ar[q*4+2] = a.z; ar[q*4+3] = a.w;
  }
  for (int j = 0; j < DH; j += 2) {
    float acc0 = sb[j], acc1 = sb[j + 1];
#pragma unroll
    for (int k = 0; k < DIN; ++k) {
      acc0 = fmaf(ar[k], swr[j*DIN+k],     fmaf(xr[k], swo[j*DIN+k],     acc0));
      acc1 = fmaf(ar[k], swr[(j+1)*DIN+k], fmaf(xr[k], swo[(j+1)*DIN+k], acc1));
    }
    // F2 row = 64 half2: [0..31]=agg2 (by gather), [32..63]=h1
    f2h[(size_t)i * 64 + 32 + (j >> 1)] =
        __floats2half2_rn(fmaxf(acc0, 0.f), fmaxf(acc1, 0.f));
  }
}

// ===================== layer-2 weight fragment prep =====================
// A-frag for D = W^T (64x128) x F^T (128x16): row(out)=lane&15, k=32kt+(lane>>4)*8+j
// element = W[k][out]: k<64 -> w2_rel[k][out] (agg), k>=64 -> w2_root[k-64][out] (h1)
__global__ __launch_bounds__(256) void k_prepw2(
    const float* __restrict__ w_rel, const float* __restrict__ w_root,
    __half* __restrict__ wf) {
  int u = blockIdx.x * 256 + threadIdx.x;   // [0,1024): mt(2b) kt(2b) lane(6b)
  if (u >= 1024) return;
  int lane = u & 63, kt = (u >> 6) & 3, mt = u >> 8;
  int out = 16 * mt + (lane & 15);
  int kb = 32 * kt + (lane >> 4) * 8;
  union { uint4 q; __half h[8]; } pk;
#pragma unroll
  for (int j = 0; j < 8; ++j) {
    int k = kb + j;
    float w = (k < 64) ? w_rel[k * DH + out] : w_root[(k - 64) * DH + out];
    pk.h[j] = __float2half(w);
  }
  *(uint4*)(wf + (size_t)u * 8) = pk.q;
}

// ===================== layer 2 (MFMA) =====================
// Per wave: 16 nodes. acc[mt] (mt=0..3) = W^T tile x F^T tile, K=128.
// Epilogue: h2 = relu(acc+b2); s = h2@w3_rel, t = h2@w3_root (never store h2).
__global__ __launch_bounds__(256) void k_l2mfma(
    const _Float16* __restrict__ F2, const _Float16* __restrict__ WF,
    const float* __restrict__ b2, const float* __restrict__ w3rel,
    const float* __restrict__ w3root,
    float* __restrict__ S, float* __restrict__ T, int n) {
  int lane = threadIdx.x & 63;
  int wv = (blockIdx.x * 256 + threadIdx.x) >> 6;
  int nb = wv * 16;
  if (nb >= n) return;
  int node = nb + (lane & 15);
  int nodeld = min(node, n - 1);
  const _Float16* fp = F2 + (size_t)nodeld * 128 + (lane >> 4) * 8;
  f16x8 bf[4];
#pragma unroll
  for (int kt = 0; kt < 4; ++kt) bf[kt] = *(const f16x8*)(fp + kt * 32);
  const f16x8* ap = (const f16x8*)WF + lane;
  f32x4 acc[4];
#pragma unroll
  for (int mt = 0; mt < 4; ++mt) acc[mt] = (f32x4)(0.f);
#pragma unroll
  for (int mt = 0; mt < 4; ++mt)
#pragma unroll
    for (int kt = 0; kt < 4; ++kt)
      acc[mt] = __builtin_amdgcn_mfma_f32_16x16x32_f16(
          ap[(mt * 4 + kt) * 64], bf[kt], acc[mt], 0, 0, 0);
  int jb = (lane >> 4) * 4;
  float s = 0.f, t = 0.f;
#pragma unroll
  for (int mt = 0; mt < 4; ++mt) {
    f32x4 vb = *(const f32x4*)(b2 + 16 * mt + jb);
    f32x4 vr = *(const f32x4*)(w3rel + 16 * mt + jb);
    f32x4 vt = *(const f32x4*)(w3root + 16 * mt + jb);
#pragma unroll
    for (int r = 0; r < 4; ++r) {
      float h = fmaxf(acc[mt][r] + vb[r], 0.f);
      s = fmaf(h, vr[r], s);
      t = fmaf(h, vt[r], t);
    }
  }
  s += __shfl_xor(s, 16); s += __shfl_xor(s, 32);
  t += __shfl_xor(t, 16); t += __shfl_xor(t, 32);
  if (lane < 16 && node < n) { S[node] = s; T[node] = t; }
}

// ===================== final: out = segsum(S) + b3 + T =====================

__global__ __launch_bounds__(256) void k_final(
    const float* __restrict__ sv, const int* __restrict__ rp,
    const int* __restrict__ ssrc, const float* __restrict__ T,
    const float* __restrict__ b3, float* __restrict__ out, int n) {
  int i = blockIdx.x * 256 + threadIdx.x;
  if (i >= n) return;
  int beg = rp[i], end = rp[i + 1];
  float a = b3[0] + T[i];
  int e = beg;
  for (; e + 3 < end; e += 4) {
    float v0 = sv[ssrc[e]];
    float v1 = sv[ssrc[e + 1]];
    float v2 = sv[ssrc[e + 2]];
    float v3 = sv[ssrc[e + 3]];
    a += v0; a += v1; a += v2; a += v3;
  }
  for (; e < end; ++e) a += sv[ssrc[e]];
  out[i] = a;
}

// ===================== launch =====================

extern "C" void kernel_launch(void* const* d_in, const int* in_sizes, int n_in,
                              void* d_out, int out_size, void* d_ws, size_t ws_size,
                              hipStream_t stream) {
  const float* x       = (const float*)d_in[0];
  const float* w1_rel  = (const float*)d_in[1];
  const float* b1      = (const float*)d_in[2];
  const float* w1_root = (const float*)d_in[3];
  const float* w2_rel  = (const float*)d_in[4];
  const float* b2      = (const float*)d_in[5];
  const float* w2_root = (const float*)d_in[6];
  const float* w3_rel  = (const float*)d_in[7];
  const float* b3      = (const float*)d_in[8];
  const float* w3_root = (const float*)d_in[9];
  const int*   edge    = (const int*)d_in[10];

  const int n = in_sizes[0] / DIN;        // 100000 (< 2^17 for packing)
  const int E = in_sizes[10] / 2;         // 1600000
  const int* src = edge;
  const int* dst = edge + E;

  float*    AGG = (float*)d_ws;                       // n*32 f32 (layer1 agg)
  _Float16* F2  = (_Float16*)(AGG + (size_t)n * 32);  // n*128 halfs
  __half2*  XH  = (__half2*)(F2 + (size_t)n * 128);   // n*16 half2
  float*    S   = (float*)(XH + (size_t)n * 16);      // n
  float*    T   = S + n;                              // n
  int* RP   = (int*)(T + n);                          // n+1 (padded to n+8)
  int* CUR  = RP + ((n + 8) & ~7);                    // n
  int* SSRC = CUR + n;                                // E
  int* BSUM = SSRC + E;                               // 256
  int* BCUR = BSUM + 256;                             // 512
  __half* WF2 = (__half*)(BCUR + 512);                // 8192 halfs (16B-aligned)
  unsigned* BIN = (unsigned*)F2;                      // E (dead before F2 writes)

  const int B = 256;
  const int gn = (n + B - 1) / B;
  const int gE = (E + B - 1) / B;
  const int nb = (n + 1023) / 1024;
  const int nbuckets = (n + 255) >> NBSHIFT;
  const int gA = (E + TILE_A - 1) / TILE_A;

  // ---- CSR build (two-level counting sort by dst) ----
  hipMemsetAsync(CUR, 0, (size_t)n * sizeof(int), stream);
  k_hist<<<gE, B, 0, stream>>>(dst, CUR, E);
  k_scan1<<<nb, B, 0, stream>>>(CUR, RP, BSUM, n);
  k_scan2<<<1, B, 0, stream>>>(BSUM, nb);
  k_scan3<<<(n + 1 + B - 1) / B, B, 0, stream>>>(RP, BSUM, BCUR, n, E);
  k_binA<<<gA, B, 0, stream>>>(src, dst, BCUR, BIN, E, nbuckets);
  k_fillB<<<nbuckets, B, 0, stream>>>(BIN, RP, SSRC, n);

  // ---- weight prep + x->fp16 ----
  k_prepw2<<<4, B, 0, stream>>>(w2_rel, w2_root, WF2);
  {
    int n2 = n * (DIN / 2);
    k_tohalf<<<(n2 + B - 1) / B, B, 0, stream>>>((const float2*)x, XH, n2);
  }

  // ---- layer 1 ---- (gather x -> AGG f32; dense -> h1 fp16 into F2[64..127])
  {
    long long tot = (long long)n * (DIN / 2);
    k_gather<4, 16, 0, 0, false><<<(unsigned)((tot + B - 1) / B), B, 0, stream>>>(
        XH, RP, SSRC, AGG, n);
  }
  layer1_kernel<<<gn, B, 0, stream>>>(x, AGG, w1_rel, b1, w1_root, (__half2*)F2, n);

  // ---- layer 2 ---- (gather h1 -> agg2 fp16 into F2[0..63]; MFMA)
  {
    long long tot = (long long)n * (DH / 2);
    k_gather<5, 64, 32, 0, true><<<(unsigned)((tot + B - 1) / B), B, 0, stream>>>(
        (const __half2*)F2, RP, SSRC, F2, n);
  }
  {
    int waves = (n + 15) / 16;
    int blocks = (waves + 3) / 4;
    k_l2mfma<<<blocks, B, 0, stream>>>(F2, (const _Float16*)WF2,
                                       b2, w3_rel, w3_root, S, T, n);
  }

  // ---- layer 3 ----
  k_final<<<gn, B, 0, stream>>>(S, RP, SSRC, T, b3, (float*)d_out, n);
}

// Round 7
// 213.102 us; speedup vs baseline: 1.5662x; 1.2806x over previous
//
#include <hip/hip_runtime.h>
#include <hip/hip_fp16.h>

typedef _Float16 f16x8 __attribute__((ext_vector_type(8)));
typedef float    f32x4 __attribute__((ext_vector_type(4)));

constexpr int DIN = 32;
constexpr int DH  = 64;
constexpr int NBSHIFT = 8;            // 256 nodes per coarse bucket
constexpr int TILE_A  = 16384;        // edges per phase-A block

// ===================== CSR build (coarse-first two-level sort) ==============

// coarse histogram: per-block LDS hist of 391 buckets, merged via ~4 atomics/bucket/block
__global__ __launch_bounds__(256) void k_chist(
    const int* __restrict__ dst, int* __restrict__ ch, int E, int nbuckets) {
  __shared__ int hist[512];
  long long t0 = (long long)blockIdx.x * TILE_A;
  int cnt = (int)min((long long)TILE_A, (long long)E - t0);
  for (int i = threadIdx.x; i < nbuckets; i += 256) hist[i] = 0;
  __syncthreads();
  for (int r = threadIdx.x; r < cnt; r += 256)
    atomicAdd(&hist[dst[t0 + r] >> NBSHIFT], 1);
  __syncthreads();
  for (int i = threadIdx.x; i < nbuckets; i += 256)
    if (hist[i]) atomicAdd(&ch[i], hist[i]);
}

// single-block exclusive scan of the coarse histogram -> CB bases + BCUR init
__global__ __launch_bounds__(256) void k_cscan(
    const int* __restrict__ ch, int* __restrict__ cb, int* __restrict__ bcur,
    int nbuckets, int E) {
  __shared__ int ts[256];
  int i0 = threadIdx.x * 2, i1 = i0 + 1;
  int v0 = (i0 < nbuckets) ? ch[i0] : 0;
  int v1 = (i1 < nbuckets) ? ch[i1] : 0;
  int s = v0 + v1;
  ts[threadIdx.x] = s;
  __syncthreads();
  for (int off = 1; off < 256; off <<= 1) {
    int val = (threadIdx.x >= off) ? ts[threadIdx.x - off] : 0;
    __syncthreads();
    ts[threadIdx.x] += val;
    __syncthreads();
  }
  int ex = ts[threadIdx.x] - s;           // exclusive prefix of this pair
  if (i0 < nbuckets) { cb[i0] = ex;      bcur[i0] = ex; }
  if (i1 < nbuckets) { cb[i1] = ex + v0; bcur[i1] = ex + v0; }
  if (threadIdx.x == 255) cb[nbuckets] = E;
}

// Phase A: bin edges into coarse dst-buckets, packed as (dst&255)<<17 | src.
// Requires n < 2^17 (n = 100000 here).
__global__ __launch_bounds__(256) void k_binA(
    const int* __restrict__ src, const int* __restrict__ dst,
    int* __restrict__ bcur, unsigned* __restrict__ bin,
    int E, int nbuckets) {
  __shared__ int hist[512];
  __shared__ int base[512];
  long long t0 = (long long)blockIdx.x * TILE_A;
  int cnt = (int)min((long long)TILE_A, (long long)E - t0);
  for (int i = threadIdx.x; i < nbuckets; i += 256) hist[i] = 0;
  __syncthreads();
  for (int r = threadIdx.x; r < cnt; r += 256)
    atomicAdd(&hist[dst[t0 + r] >> NBSHIFT], 1);
  __syncthreads();
  for (int i = threadIdx.x; i < nbuckets; i += 256) {
    int c = hist[i];
    base[i] = c ? atomicAdd(&bcur[i], c) : 0;
    hist[i] = 0;
  }
  __syncthreads();
  for (int r = threadIdx.x; r < cnt; r += 256) {
    int d = dst[t0 + r];
    int s = src[t0 + r];
    int b = d >> NBSHIFT;
    int off = atomicAdd(&hist[b], 1);
    bin[base[b] + off] = ((unsigned)(d & 255) << 17) | (unsigned)s;
  }
}

// Phase B: fine-degree LDS histogram + scan (writes rp), then exact scatter
__global__ __launch_bounds__(256) void k_fillB(
    const unsigned* __restrict__ bin, const int* __restrict__ cb,
    int* __restrict__ rp, int* __restrict__ ssrc, int n, int E) {
  __shared__ int deg[256];
  __shared__ int ts[256];
  __shared__ int cur[256];
  int b = blockIdx.x;
  int nbase = b << NBSHIFT;
  int nn = min(256, n - nbase);
  int ebeg = cb[b], eend = cb[b + 1];
  deg[threadIdx.x] = 0;
  __syncthreads();
  for (int e = ebeg + (int)threadIdx.x; e < eend; e += 256)
    atomicAdd(&deg[bin[e] >> 17], 1);
  __syncthreads();
  int d = deg[threadIdx.x];
  ts[threadIdx.x] = d;
  __syncthreads();
  for (int off = 1; off < 256; off <<= 1) {
    int val = (threadIdx.x >= off) ? ts[threadIdx.x - off] : 0;
    __syncthreads();
    ts[threadIdx.x] += val;
    __syncthreads();
  }
  int pref = ts[threadIdx.x] - d;        // intra-bucket exclusive prefix
  if ((int)threadIdx.x < nn) {
    rp[nbase + threadIdx.x] = ebeg + pref;
    cur[threadIdx.x] = ebeg + pref;
  }
  if (b == 0 && threadIdx.x == 0) rp[n] = E;
  __syncthreads();
  for (int e = ebeg + (int)threadIdx.x; e < eend; e += 256) {
    unsigned u = bin[e];
    int dlow = (int)(u >> 17);
    int s = (int)(u & 0x1FFFF);
    int pos = atomicAdd(&cur[dlow], 1);
    ssrc[pos] = s;
  }
}

// ===================== fp32 -> fp16 =====================

__global__ __launch_bounds__(256) void k_tohalf(
    const float2* __restrict__ in, __half2* __restrict__ out, int n2) {
  int i = blockIdx.x * 256 + threadIdx.x;
  if (i >= n2) return;
  float2 v = in[i];
  out[i] = __floats2half2_rn(v.x, v.y);
}

// ===================== gather segment sums =====================
// 1<<LOGG half2-lanes per node; feat rows are LDH2 half2 wide, read at OFFR.
// OUTH: write half2 at row stride LDH2, offset OFFW; else float2 contiguous.
template<int LOGG, int LDH2, int OFFR, int OFFW, bool OUTH>
__global__ __launch_bounds__(256) void k_gather(
    const __half2* __restrict__ feat, const int* __restrict__ rp,
    const int* __restrict__ ssrc, void* __restrict__ outp, int n) {
  int t = blockIdx.x * 256 + threadIdx.x;
  int node = t >> LOGG;
  int f2 = t & ((1 << LOGG) - 1);
  if (node >= n) return;
  int beg = rp[node], end = rp[node + 1];
  float ax = 0.f, ay = 0.f;
  int e = beg;
  for (; e + 3 < end; e += 4) {
    int s0 = ssrc[e];
    int s1 = ssrc[e + 1];
    int s2 = ssrc[e + 2];
    int s3 = ssrc[e + 3];
    float2 v0 = __half22float2(feat[(size_t)s0 * LDH2 + OFFR + f2]);
    float2 v1 = __half22float2(feat[(size_t)s1 * LDH2 + OFFR + f2]);
    float2 v2 = __half22float2(feat[(size_t)s2 * LDH2 + OFFR + f2]);
    float2 v3 = __half22float2(feat[(size_t)s3 * LDH2 + OFFR + f2]);
    ax += v0.x; ay += v0.y;
    ax += v1.x; ay += v1.y;
    ax += v2.x; ay += v2.y;
    ax += v3.x; ay += v3.y;
  }
  for (; e < end; ++e) {
    float2 v = __half22float2(feat[(size_t)ssrc[e] * LDH2 + OFFR + f2]);
    ax += v.x; ay += v.y;
  }
  if (OUTH) {
    ((__half2*)outp)[(size_t)node * LDH2 + OFFW + f2] = __floats2half2_rn(ax, ay);
  } else {
    ((float2*)outp)[((size_t)node << LOGG) + f2] = make_float2(ax, ay);
  }
}

// ===================== layer 1 (VALU) =====================
// h1 = relu(agg@w1_rel + b1 + x@w1_root) -> fp16 into F2[node][64..127]

__global__ __launch_bounds__(256) void layer1_kernel(
    const float* __restrict__ x, const float* __restrict__ agg,
    const float* __restrict__ w_rel, const float* __restrict__ b,
    const float* __restrict__ w_root, __half2* __restrict__ f2h, int n) {
  __shared__ float swr[DH * DIN];   // [j][k], linear writes
  __shared__ float swo[DH * DIN];
  __shared__ float sb[DH];
  for (int idx = threadIdx.x; idx < DIN * DH; idx += blockDim.x) {
    int j = idx / DIN, k = idx % DIN;
    swr[idx] = w_rel[k * DH + j];
    swo[idx] = w_root[k * DH + j];
  }
  if (threadIdx.x < DH) sb[threadIdx.x] = b[threadIdx.x];
  __syncthreads();
  int i = blockIdx.x * blockDim.x + threadIdx.x;
  if (i >= n) return;
  float xr[DIN], ar[DIN];
  const float4* xp = (const float4*)(x + (size_t)i * DIN);
  const float4* ap = (const float4*)(agg + (size_t)i * DIN);
#pragma unroll
  for (int q = 0; q < DIN / 4; ++q) {
    float4 v = xp[q];
    xr[q*4+0] = v.x; xr[q*4+1] = v.y; xr[q*4+2] = v.z; xr[q*4+3] = v.w;
    float4 a = ap[q];
    ar[q*4+0] = a.x; ar[q*4+1] = a.y; ar[q*4+2] = a.z; ar[q*4+3] = a.w;
  }
  for (int j = 0; j < DH; j += 2) {
    float acc0 = sb[j], acc1 = sb[j + 1];
#pragma unroll
    for (int k = 0; k < DIN; ++k) {
      acc0 = fmaf(ar[k], swr[j*DIN+k],     fmaf(xr[k], swo[j*DIN+k],     acc0));
      acc1 = fmaf(ar[k], swr[(j+1)*DIN+k], fmaf(xr[k], swo[(j+1)*DIN+k], acc1));
    }
    // F2 row = 64 half2: [0..31]=agg2 (by gather), [32..63]=h1
    f2h[(size_t)i * 64 + 32 + (j >> 1)] =
        __floats2half2_rn(fmaxf(acc0, 0.f), fmaxf(acc1, 0.f));
  }
}

// ===================== layer-2 weight fragment prep =====================
// A-frag for D = W^T (64x128) x F^T (128x16): row(out)=lane&15, k=32kt+(lane>>4)*8+j
// element = W[k][out]: k<64 -> w2_rel[k][out] (agg), k>=64 -> w2_root[k-64][out] (h1)
__global__ __launch_bounds__(256) void k_prepw2(
    const float* __restrict__ w_rel, const float* __restrict__ w_root,
    __half* __restrict__ wf) {
  int u = blockIdx.x * 256 + threadIdx.x;   // [0,1024): mt(2b) kt(2b) lane(6b)
  if (u >= 1024) return;
  int lane = u & 63, kt = (u >> 6) & 3, mt = u >> 8;
  int out = 16 * mt + (lane & 15);
  int kb = 32 * kt + (lane >> 4) * 8;
  union { uint4 q; __half h[8]; } pk;
#pragma unroll
  for (int j = 0; j < 8; ++j) {
    int k = kb + j;
    float w = (k < 64) ? w_rel[k * DH + out] : w_root[(k - 64) * DH + out];
    pk.h[j] = __float2half(w);
  }
  *(uint4*)(wf + (size_t)u * 8) = pk.q;
}

// ===================== layer 2 (MFMA) =====================
__global__ __launch_bounds__(256) void k_l2mfma(
    const _Float16* __restrict__ F2, const _Float16* __restrict__ WF,
    const float* __restrict__ b2, const float* __restrict__ w3rel,
    const float* __restrict__ w3root,
    float* __restrict__ S, float* __restrict__ T, int n) {
  int lane = threadIdx.x & 63;
  int wv = (blockIdx.x * 256 + threadIdx.x) >> 6;
  int nb = wv * 16;
  if (nb >= n) return;
  int node = nb + (lane & 15);
  int nodeld = min(node, n - 1);
  const _Float16* fp = F2 + (size_t)nodeld * 128 + (lane >> 4) * 8;
  f16x8 bf[4];
#pragma unroll
  for (int kt = 0; kt < 4; ++kt) bf[kt] = *(const f16x8*)(fp + kt * 32);
  const f16x8* ap = (const f16x8*)WF + lane;
  f32x4 acc[4];
#pragma unroll
  for (int mt = 0; mt < 4; ++mt) acc[mt] = (f32x4)(0.f);
#pragma unroll
  for (int mt = 0; mt < 4; ++mt)
#pragma unroll
    for (int kt = 0; kt < 4; ++kt)
      acc[mt] = __builtin_amdgcn_mfma_f32_16x16x32_f16(
          ap[(mt * 4 + kt) * 64], bf[kt], acc[mt], 0, 0, 0);
  int jb = (lane >> 4) * 4;
  float s = 0.f, t = 0.f;
#pragma unroll
  for (int mt = 0; mt < 4; ++mt) {
    f32x4 vb = *(const f32x4*)(b2 + 16 * mt + jb);
    f32x4 vr = *(const f32x4*)(w3rel + 16 * mt + jb);
    f32x4 vt = *(const f32x4*)(w3root + 16 * mt + jb);
#pragma unroll
    for (int r = 0; r < 4; ++r) {
      float h = fmaxf(acc[mt][r] + vb[r], 0.f);
      s = fmaf(h, vr[r], s);
      t = fmaf(h, vt[r], t);
    }
  }
  s += __shfl_xor(s, 16); s += __shfl_xor(s, 32);
  t += __shfl_xor(t, 16); t += __shfl_xor(t, 32);
  if (lane < 16 && node < n) { S[node] = s; T[node] = t; }
}

// ===================== final: out = segsum(S) + b3 + T =====================

__global__ __launch_bounds__(256) void k_final(
    const float* __restrict__ sv, const int* __restrict__ rp,
    const int* __restrict__ ssrc, const float* __restrict__ T,
    const float* __restrict__ b3, float* __restrict__ out, int n) {
  int i = blockIdx.x * 256 + threadIdx.x;
  if (i >= n) return;
  int beg = rp[i], end = rp[i + 1];
  float a = b3[0] + T[i];
  int e = beg;
  for (; e + 3 < end; e += 4) {
    float v0 = sv[ssrc[e]];
    float v1 = sv[ssrc[e + 1]];
    float v2 = sv[ssrc[e + 2]];
    float v3 = sv[ssrc[e + 3]];
    a += v0; a += v1; a += v2; a += v3;
  }
  for (; e < end; ++e) a += sv[ssrc[e]];
  out[i] = a;
}

// ===================== launch =====================

extern "C" void kernel_launch(void* const* d_in, const int* in_sizes, int n_in,
                              void* d_out, int out_size, void* d_ws, size_t ws_size,
                              hipStream_t stream) {
  const float* x       = (const float*)d_in[0];
  const float* w1_rel  = (const float*)d_in[1];
  const float* b1      = (const float*)d_in[2];
  const float* w1_root = (const float*)d_in[3];
  const float* w2_rel  = (const float*)d_in[4];
  const float* b2      = (const float*)d_in[5];
  const float* w2_root = (const float*)d_in[6];
  const float* w3_rel  = (const float*)d_in[7];
  const float* b3      = (const float*)d_in[8];
  const float* w3_root = (const float*)d_in[9];
  const int*   edge    = (const int*)d_in[10];

  const int n = in_sizes[0] / DIN;        // 100000 (< 2^17 for packing)
  const int E = in_sizes[10] / 2;         // 1600000
  const int* src = edge;
  const int* dst = edge + E;

  float*    AGG = (float*)d_ws;                       // n*32 f32 (layer1 agg)
  _Float16* F2  = (_Float16*)(AGG + (size_t)n * 32);  // n*128 halfs
  __half2*  XH  = (__half2*)(F2 + (size_t)n * 128);   // n*16 half2
  float*    S   = (float*)(XH + (size_t)n * 16);      // n
  float*    T   = S + n;                              // n
  int* RP   = (int*)(T + n);                          // n+1 (pad to 8)
  int* SSRC = RP + ((n + 8) & ~7);                    // E
  int* CH   = SSRC + E;                               // 512 coarse counts
  int* CB   = CH + 512;                               // 513 coarse bases
  int* BCUR = CB + 520;                               // 512 cursors
  __half* WF2 = (__half*)(BCUR + 512);                // 8192 halfs (16B-aligned)
  unsigned* BIN = (unsigned*)F2;                      // E (dead before F2 writes)

  const int B = 256;
  const int gn = (n + B - 1) / B;
  const int nbuckets = (n + 255) >> NBSHIFT;          // 391
  const int gA = (E + TILE_A - 1) / TILE_A;           // 98

  // ---- CSR build (coarse hist -> scan -> bin -> fine fill) ----
  hipMemsetAsync(CH, 0, 512 * sizeof(int), stream);
  k_chist<<<gA, B, 0, stream>>>(dst, CH, E, nbuckets);
  k_cscan<<<1, B, 0, stream>>>(CH, CB, BCUR, nbuckets, E);
  k_binA<<<gA, B, 0, stream>>>(src, dst, BCUR, BIN, E, nbuckets);
  k_fillB<<<nbuckets, B, 0, stream>>>(BIN, CB, RP, SSRC, n, E);

  // ---- weight prep + x->fp16 ----
  k_prepw2<<<4, B, 0, stream>>>(w2_rel, w2_root, WF2);
  {
    int n2 = n * (DIN / 2);
    k_tohalf<<<(n2 + B - 1) / B, B, 0, stream>>>((const float2*)x, XH, n2);
  }

  // ---- layer 1 ---- (gather x -> AGG f32; dense -> h1 fp16 into F2[64..127])
  {
    long long tot = (long long)n * (DIN / 2);
    k_gather<4, 16, 0, 0, false><<<(unsigned)((tot + B - 1) / B), B, 0, stream>>>(
        XH, RP, SSRC, AGG, n);
  }
  layer1_kernel<<<gn, B, 0, stream>>>(x, AGG, w1_rel, b1, w1_root, (__half2*)F2, n);

  // ---- layer 2 ---- (gather h1 -> agg2 fp16 into F2[0..63]; MFMA)
  {
    long long tot = (long long)n * (DH / 2);
    k_gather<5, 64, 32, 0, true><<<(unsigned)((tot + B - 1) / B), B, 0, stream>>>(
        (const __half2*)F2, RP, SSRC, F2, n);
  }
  {
    int waves = (n + 15) / 16;
    int blocks = (waves + 3) / 4;
    k_l2mfma<<<blocks, B, 0, stream>>>(F2, (const _Float16*)WF2,
                                       b2, w3_rel, w3_root, S, T, n);
  }

  // ---- layer 3 ----
  k_final<<<gn, B, 0, stream>>>(S, RP, SSRC, T, b3, (float*)d_out, n);
}

// Round 8
// 203.894 us; speedup vs baseline: 1.6369x; 1.0452x over previous
//
#include <hip/hip_runtime.h>
#include <hip/hip_fp16.h>

typedef _Float16 f16x8 __attribute__((ext_vector_type(8)));
typedef float    f32x4 __attribute__((ext_vector_type(4)));

constexpr int DIN = 32;
constexpr int DH  = 64;
constexpr int NBSHIFT = 8;            // 256 nodes per coarse bucket
constexpr int TILE_A  = 4096;         // edges per phase-A block (391 blocks: TLP!)

// ===================== CSR build (coarse-first two-level sort) ==============

// coarse histogram: per-block LDS hist of 391 buckets, merged via atomics
__global__ __launch_bounds__(256) void k_chist(
    const int* __restrict__ dst, int* __restrict__ ch, int E, int nbuckets) {
  __shared__ int hist[512];
  long long t0 = (long long)blockIdx.x * TILE_A;
  int cnt = (int)min((long long)TILE_A, (long long)E - t0);
  for (int i = threadIdx.x; i < nbuckets; i += 256) hist[i] = 0;
  __syncthreads();
  for (int r = threadIdx.x; r < cnt; r += 256)
    atomicAdd(&hist[dst[t0 + r] >> NBSHIFT], 1);
  __syncthreads();
  for (int i = threadIdx.x; i < nbuckets; i += 256)
    if (hist[i]) atomicAdd(&ch[i], hist[i]);
}

// single-block exclusive scan of the coarse histogram -> CB bases + BCUR init
__global__ __launch_bounds__(256) void k_cscan(
    const int* __restrict__ ch, int* __restrict__ cb, int* __restrict__ bcur,
    int nbuckets, int E) {
  __shared__ int ts[256];
  int i0 = threadIdx.x * 2, i1 = i0 + 1;
  int v0 = (i0 < nbuckets) ? ch[i0] : 0;
  int v1 = (i1 < nbuckets) ? ch[i1] : 0;
  int s = v0 + v1;
  ts[threadIdx.x] = s;
  __syncthreads();
  for (int off = 1; off < 256; off <<= 1) {
    int val = (threadIdx.x >= off) ? ts[threadIdx.x - off] : 0;
    __syncthreads();
    ts[threadIdx.x] += val;
    __syncthreads();
  }
  int ex = ts[threadIdx.x] - s;           // exclusive prefix of this pair
  if (i0 < nbuckets) { cb[i0] = ex;      bcur[i0] = ex; }
  if (i1 < nbuckets) { cb[i1] = ex + v0; bcur[i1] = ex + v0; }
  if (threadIdx.x == 255) cb[nbuckets] = E;
}

// Phase A: bin edges into coarse dst-buckets, packed as (dst&255)<<17 | src.
// Requires n < 2^17 (n = 100000 here).
__global__ __launch_bounds__(256) void k_binA(
    const int* __restrict__ src, const int* __restrict__ dst,
    int* __restrict__ bcur, unsigned* __restrict__ bin,
    int E, int nbuckets) {
  __shared__ int hist[512];
  __shared__ int base[512];
  long long t0 = (long long)blockIdx.x * TILE_A;
  int cnt = (int)min((long long)TILE_A, (long long)E - t0);
  for (int i = threadIdx.x; i < nbuckets; i += 256) hist[i] = 0;
  __syncthreads();
  for (int r = threadIdx.x; r < cnt; r += 256)
    atomicAdd(&hist[dst[t0 + r] >> NBSHIFT], 1);
  __syncthreads();
  for (int i = threadIdx.x; i < nbuckets; i += 256) {
    int c = hist[i];
    base[i] = c ? atomicAdd(&bcur[i], c) : 0;
    hist[i] = 0;
  }
  __syncthreads();
  for (int r = threadIdx.x; r < cnt; r += 256) {
    int d = dst[t0 + r];
    int s = src[t0 + r];
    int b = d >> NBSHIFT;
    int off = atomicAdd(&hist[b], 1);
    bin[base[b] + off] = ((unsigned)(d & 255) << 17) | (unsigned)s;
  }
}

// Phase B: fine-degree LDS histogram + scan (writes rp), then exact scatter
__global__ __launch_bounds__(256) void k_fillB(
    const unsigned* __restrict__ bin, const int* __restrict__ cb,
    int* __restrict__ rp, int* __restrict__ ssrc, int n, int E) {
  __shared__ int deg[256];
  __shared__ int ts[256];
  __shared__ int cur[256];
  int b = blockIdx.x;
  int nbase = b << NBSHIFT;
  int nn = min(256, n - nbase);
  int ebeg = cb[b], eend = cb[b + 1];
  deg[threadIdx.x] = 0;
  __syncthreads();
  for (int e = ebeg + (int)threadIdx.x; e < eend; e += 256)
    atomicAdd(&deg[bin[e] >> 17], 1);
  __syncthreads();
  int d = deg[threadIdx.x];
  ts[threadIdx.x] = d;
  __syncthreads();
  for (int off = 1; off < 256; off <<= 1) {
    int val = (threadIdx.x >= off) ? ts[threadIdx.x - off] : 0;
    __syncthreads();
    ts[threadIdx.x] += val;
    __syncthreads();
  }
  int pref = ts[threadIdx.x] - d;        // intra-bucket exclusive prefix
  if ((int)threadIdx.x < nn) {
    rp[nbase + threadIdx.x] = ebeg + pref;
    cur[threadIdx.x] = ebeg + pref;
  }
  if (b == 0 && threadIdx.x == 0) rp[n] = E;
  __syncthreads();
  for (int e = ebeg + (int)threadIdx.x; e < eend; e += 256) {
    unsigned u = bin[e];
    int dlow = (int)(u >> 17);
    int s = (int)(u & 0x1FFFF);
    int pos = atomicAdd(&cur[dlow], 1);
    ssrc[pos] = s;
  }
}

// ===================== fp32 -> fp16 =====================

__global__ __launch_bounds__(256) void k_tohalf(
    const float2* __restrict__ in, __half2* __restrict__ out, int n2) {
  int i = blockIdx.x * 256 + threadIdx.x;
  if (i >= n2) return;
  float2 v = in[i];
  out[i] = __floats2half2_rn(v.x, v.y);
}

// ===================== gather segment sums =====================
// 1<<LOGG half2-lanes per node; feat rows are LDH2 half2 wide, read at OFFR.
// OUTH: write half2 at row stride LDH2, offset OFFW; else float2 contiguous.
template<int LOGG, int LDH2, int OFFR, int OFFW, bool OUTH>
__global__ __launch_bounds__(256) void k_gather(
    const __half2* __restrict__ feat, const int* __restrict__ rp,
    const int* __restrict__ ssrc, void* __restrict__ outp, int n) {
  int t = blockIdx.x * 256 + threadIdx.x;
  int node = t >> LOGG;
  int f2 = t & ((1 << LOGG) - 1);
  if (node >= n) return;
  int beg = rp[node], end = rp[node + 1];
  float ax = 0.f, ay = 0.f;
  int e = beg;
  for (; e + 3 < end; e += 4) {
    int s0 = ssrc[e];
    int s1 = ssrc[e + 1];
    int s2 = ssrc[e + 2];
    int s3 = ssrc[e + 3];
    float2 v0 = __half22float2(feat[(size_t)s0 * LDH2 + OFFR + f2]);
    float2 v1 = __half22float2(feat[(size_t)s1 * LDH2 + OFFR + f2]);
    float2 v2 = __half22float2(feat[(size_t)s2 * LDH2 + OFFR + f2]);
    float2 v3 = __half22float2(feat[(size_t)s3 * LDH2 + OFFR + f2]);
    ax += v0.x; ay += v0.y;
    ax += v1.x; ay += v1.y;
    ax += v2.x; ay += v2.y;
    ax += v3.x; ay += v3.y;
  }
  for (; e < end; ++e) {
    float2 v = __half22float2(feat[(size_t)ssrc[e] * LDH2 + OFFR + f2]);
    ax += v.x; ay += v.y;
  }
  if (OUTH) {
    ((__half2*)outp)[(size_t)node * LDH2 + OFFW + f2] = __floats2half2_rn(ax, ay);
  } else {
    ((float2*)outp)[((size_t)node << LOGG) + f2] = make_float2(ax, ay);
  }
}

// ===================== layer 1 (VALU) =====================
// h1 = relu(agg@w1_rel + b1 + x@w1_root) -> fp16 into F2[node][64..127]

__global__ __launch_bounds__(256) void layer1_kernel(
    const float* __restrict__ x, const float* __restrict__ agg,
    const float* __restrict__ w_rel, const float* __restrict__ b,
    const float* __restrict__ w_root, __half2* __restrict__ f2h, int n) {
  __shared__ float swr[DH * DIN];   // [j][k], linear writes
  __shared__ float swo[DH * DIN];
  __shared__ float sb[DH];
  for (int idx = threadIdx.x; idx < DIN * DH; idx += blockDim.x) {
    int j = idx / DIN, k = idx % DIN;
    swr[idx] = w_rel[k * DH + j];
    swo[idx] = w_root[k * DH + j];
  }
  if (threadIdx.x < DH) sb[threadIdx.x] = b[threadIdx.x];
  __syncthreads();
  int i = blockIdx.x * blockDim.x + threadIdx.x;
  if (i >= n) return;
  float xr[DIN], ar[DIN];
  const float4* xp = (const float4*)(x + (size_t)i * DIN);
  const float4* ap = (const float4*)(agg + (size_t)i * DIN);
#pragma unroll
  for (int q = 0; q < DIN / 4; ++q) {
    float4 v = xp[q];
    xr[q*4+0] = v.x; xr[q*4+1] = v.y; xr[q*4+2] = v.z; xr[q*4+3] = v.w;
    float4 a = ap[q];
    ar[q*4+0] = a.x; ar[q*4+1] = a.y; ar[q*4+2] = a.z; ar[q*4+3] = a.w;
  }
  for (int j = 0; j < DH; j += 2) {
    float acc0 = sb[j], acc1 = sb[j + 1];
#pragma unroll
    for (int k = 0; k < DIN; ++k) {
      acc0 = fmaf(ar[k], swr[j*DIN+k],     fmaf(xr[k], swo[j*DIN+k],     acc0));
      acc1 = fmaf(ar[k], swr[(j+1)*DIN+k], fmaf(xr[k], swo[(j+1)*DIN+k], acc1));
    }
    // F2 row = 64 half2: [0..31]=agg2 (by gather), [32..63]=h1
    f2h[(size_t)i * 64 + 32 + (j >> 1)] =
        __floats2half2_rn(fmaxf(acc0, 0.f), fmaxf(acc1, 0.f));
  }
}

// ===================== layer-2 weight fragment prep =====================
// A-frag for D = W^T (64x128) x F^T (128x16): row(out)=lane&15, k=32kt+(lane>>4)*8+j
// element = W[k][out]: k<64 -> w2_rel[k][out] (agg), k>=64 -> w2_root[k-64][out] (h1)
__global__ __launch_bounds__(256) void k_prepw2(
    const float* __restrict__ w_rel, const float* __restrict__ w_root,
    __half* __restrict__ wf) {
  int u = blockIdx.x * 256 + threadIdx.x;   // [0,1024): mt(2b) kt(2b) lane(6b)
  if (u >= 1024) return;
  int lane = u & 63, kt = (u >> 6) & 3, mt = u >> 8;
  int out = 16 * mt + (lane & 15);
  int kb = 32 * kt + (lane >> 4) * 8;
  union { uint4 q; __half h[8]; } pk;
#pragma unroll
  for (int j = 0; j < 8; ++j) {
    int k = kb + j;
    float w = (k < 64) ? w_rel[k * DH + out] : w_root[(k - 64) * DH + out];
    pk.h[j] = __float2half(w);
  }
  *(uint4*)(wf + (size_t)u * 8) = pk.q;
}

// ===================== layer 2 (MFMA) =====================
__global__ __launch_bounds__(256) void k_l2mfma(
    const _Float16* __restrict__ F2, const _Float16* __restrict__ WF,
    const float* __restrict__ b2, const float* __restrict__ w3rel,
    const float* __restrict__ w3root,
    float* __restrict__ S, float* __restrict__ T, int n) {
  int lane = threadIdx.x & 63;
  int wv = (blockIdx.x * 256 + threadIdx.x) >> 6;
  int nb = wv * 16;
  if (nb >= n) return;
  int node = nb + (lane & 15);
  int nodeld = min(node, n - 1);
  const _Float16* fp = F2 + (size_t)nodeld * 128 + (lane >> 4) * 8;
  f16x8 bf[4];
#pragma unroll
  for (int kt = 0; kt < 4; ++kt) bf[kt] = *(const f16x8*)(fp + kt * 32);
  const f16x8* ap = (const f16x8*)WF + lane;
  f32x4 acc[4];
#pragma unroll
  for (int mt = 0; mt < 4; ++mt) acc[mt] = (f32x4)(0.f);
#pragma unroll
  for (int mt = 0; mt < 4; ++mt)
#pragma unroll
    for (int kt = 0; kt < 4; ++kt)
      acc[mt] = __builtin_amdgcn_mfma_f32_16x16x32_f16(
          ap[(mt * 4 + kt) * 64], bf[kt], acc[mt], 0, 0, 0);
  int jb = (lane >> 4) * 4;
  float s = 0.f, t = 0.f;
#pragma unroll
  for (int mt = 0; mt < 4; ++mt) {
    f32x4 vb = *(const f32x4*)(b2 + 16 * mt + jb);
    f32x4 vr = *(const f32x4*)(w3rel + 16 * mt + jb);
    f32x4 vt = *(const f32x4*)(w3root + 16 * mt + jb);
#pragma unroll
    for (int r = 0; r < 4; ++r) {
      float h = fmaxf(acc[mt][r] + vb[r], 0.f);
      s = fmaf(h, vr[r], s);
      t = fmaf(h, vt[r], t);
    }
  }
  s += __shfl_xor(s, 16); s += __shfl_xor(s, 32);
  t += __shfl_xor(t, 16); t += __shfl_xor(t, 32);
  if (lane < 16 && node < n) { S[node] = s; T[node] = t; }
}

// ===================== final: out = segsum(S) + b3 + T =====================

__global__ __launch_bounds__(256) void k_final(
    const float* __restrict__ sv, const int* __restrict__ rp,
    const int* __restrict__ ssrc, const float* __restrict__ T,
    const float* __restrict__ b3, float* __restrict__ out, int n) {
  int i = blockIdx.x * 256 + threadIdx.x;
  if (i >= n) return;
  int beg = rp[i], end = rp[i + 1];
  float a = b3[0] + T[i];
  int e = beg;
  for (; e + 3 < end; e += 4) {
    float v0 = sv[ssrc[e]];
    float v1 = sv[ssrc[e + 1]];
    float v2 = sv[ssrc[e + 2]];
    float v3 = sv[ssrc[e + 3]];
    a += v0; a += v1; a += v2; a += v3;
  }
  for (; e < end; ++e) a += sv[ssrc[e]];
  out[i] = a;
}

// ===================== launch =====================

extern "C" void kernel_launch(void* const* d_in, const int* in_sizes, int n_in,
                              void* d_out, int out_size, void* d_ws, size_t ws_size,
                              hipStream_t stream) {
  const float* x       = (const float*)d_in[0];
  const float* w1_rel  = (const float*)d_in[1];
  const float* b1      = (const float*)d_in[2];
  const float* w1_root = (const float*)d_in[3];
  const float* w2_rel  = (const float*)d_in[4];
  const float* b2      = (const float*)d_in[5];
  const float* w2_root = (const float*)d_in[6];
  const float* w3_rel  = (const float*)d_in[7];
  const float* b3      = (const float*)d_in[8];
  const float* w3_root = (const float*)d_in[9];
  const int*   edge    = (const int*)d_in[10];

  const int n = in_sizes[0] / DIN;        // 100000 (< 2^17 for packing)
  const int E = in_sizes[10] / 2;         // 1600000
  const int* src = edge;
  const int* dst = edge + E;

  float*    AGG = (float*)d_ws;                       // n*32 f32 (layer1 agg)
  _Float16* F2  = (_Float16*)(AGG + (size_t)n * 32);  // n*128 halfs
  __half2*  XH  = (__half2*)(F2 + (size_t)n * 128);   // n*16 half2
  float*    S   = (float*)(XH + (size_t)n * 16);      // n
  float*    T   = S + n;                              // n
  int* RP   = (int*)(T + n);                          // n+1 (pad to 8)
  int* SSRC = RP + ((n + 8) & ~7);                    // E
  int* CH   = SSRC + E;                               // 512 coarse counts
  int* CB   = CH + 512;                               // 513 coarse bases
  int* BCUR = CB + 520;                               // 512 cursors
  __half* WF2 = (__half*)(BCUR + 512);                // 8192 halfs (16B-aligned)
  unsigned* BIN = (unsigned*)F2;                      // E (dead before F2 writes)

  const int B = 256;
  const int gn = (n + B - 1) / B;
  const int nbuckets = (n + 255) >> NBSHIFT;          // 391
  const int gA = (E + TILE_A - 1) / TILE_A;           // 391

  // ---- CSR build (coarse hist -> scan -> bin -> fine fill) ----
  hipMemsetAsync(CH, 0, 512 * sizeof(int), stream);
  k_chist<<<gA, B, 0, stream>>>(dst, CH, E, nbuckets);
  k_cscan<<<1, B, 0, stream>>>(CH, CB, BCUR, nbuckets, E);
  k_binA<<<gA, B, 0, stream>>>(src, dst, BCUR, BIN, E, nbuckets);
  k_fillB<<<nbuckets, B, 0, stream>>>(BIN, CB, RP, SSRC, n, E);

  // ---- weight prep + x->fp16 ----
  k_prepw2<<<4, B, 0, stream>>>(w2_rel, w2_root, WF2);
  {
    int n2 = n * (DIN / 2);
    k_tohalf<<<(n2 + B - 1) / B, B, 0, stream>>>((const float2*)x, XH, n2);
  }

  // ---- layer 1 ---- (gather x -> AGG f32; dense -> h1 fp16 into F2[64..127])
  {
    long long tot = (long long)n * (DIN / 2);
    k_gather<4, 16, 0, 0, false><<<(unsigned)((tot + B - 1) / B), B, 0, stream>>>(
        XH, RP, SSRC, AGG, n);
  }
  layer1_kernel<<<gn, B, 0, stream>>>(x, AGG, w1_rel, b1, w1_root, (__half2*)F2, n);

  // ---- layer 2 ---- (gather h1 -> agg2 fp16 into F2[0..63]; MFMA)
  {
    long long tot = (long long)n * (DH / 2);
    k_gather<5, 64, 32, 0, true><<<(unsigned)((tot + B - 1) / B), B, 0, stream>>>(
        (const __half2*)F2, RP, SSRC, F2, n);
  }
  {
    int waves = (n + 15) / 16;
    int blocks = (waves + 3) / 4;
    k_l2mfma<<<blocks, B, 0, stream>>>(F2, (const _Float16*)WF2,
                                       b2, w3_rel, w3_root, S, T, n);
  }

  // ---- layer 3 ----
  k_final<<<gn, B, 0, stream>>>(S, RP, SSRC, T, b3, (float*)d_out, n);
}

// Round 9
// 180.284 us; speedup vs baseline: 1.8513x; 1.1310x over previous
//
#include <hip/hip_runtime.h>
#include <hip/hip_fp16.h>

typedef _Float16 f16x8 __attribute__((ext_vector_type(8)));
typedef float    f32x4 __attribute__((ext_vector_type(4)));

constexpr int DIN = 32;
constexpr int DH  = 64;
constexpr int NBSHIFT = 8;            // 256 nodes per coarse bucket
constexpr int TILE_A  = 4096;         // edges per phase-A block (391 blocks)

// ===================== CSR build (coarse-first two-level sort) ==============

__global__ __launch_bounds__(256) void k_chist(
    const int* __restrict__ dst, int* __restrict__ ch, int E, int nbuckets) {
  __shared__ int hist[512];
  long long t0 = (long long)blockIdx.x * TILE_A;
  int cnt = (int)min((long long)TILE_A, (long long)E - t0);
  for (int i = threadIdx.x; i < nbuckets; i += 256) hist[i] = 0;
  __syncthreads();
  for (int r = threadIdx.x; r < cnt; r += 256)
    atomicAdd(&hist[dst[t0 + r] >> NBSHIFT], 1);
  __syncthreads();
  for (int i = threadIdx.x; i < nbuckets; i += 256)
    if (hist[i]) atomicAdd(&ch[i], hist[i]);
}

__global__ __launch_bounds__(256) void k_cscan(
    const int* __restrict__ ch, int* __restrict__ cb, int* __restrict__ bcur,
    int nbuckets, int E) {
  __shared__ int ts[256];
  int i0 = threadIdx.x * 2, i1 = i0 + 1;
  int v0 = (i0 < nbuckets) ? ch[i0] : 0;
  int v1 = (i1 < nbuckets) ? ch[i1] : 0;
  int s = v0 + v1;
  ts[threadIdx.x] = s;
  __syncthreads();
  for (int off = 1; off < 256; off <<= 1) {
    int val = (threadIdx.x >= off) ? ts[threadIdx.x - off] : 0;
    __syncthreads();
    ts[threadIdx.x] += val;
    __syncthreads();
  }
  int ex = ts[threadIdx.x] - s;
  if (i0 < nbuckets) { cb[i0] = ex;      bcur[i0] = ex; }
  if (i1 < nbuckets) { cb[i1] = ex + v0; bcur[i1] = ex + v0; }
  if (threadIdx.x == 255) cb[nbuckets] = E;
}

__global__ __launch_bounds__(256) void k_binA(
    const int* __restrict__ src, const int* __restrict__ dst,
    int* __restrict__ bcur, unsigned* __restrict__ bin,
    int E, int nbuckets) {
  __shared__ int hist[512];
  __shared__ int base[512];
  long long t0 = (long long)blockIdx.x * TILE_A;
  int cnt = (int)min((long long)TILE_A, (long long)E - t0);
  for (int i = threadIdx.x; i < nbuckets; i += 256) hist[i] = 0;
  __syncthreads();
  for (int r = threadIdx.x; r < cnt; r += 256)
    atomicAdd(&hist[dst[t0 + r] >> NBSHIFT], 1);
  __syncthreads();
  for (int i = threadIdx.x; i < nbuckets; i += 256) {
    int c = hist[i];
    base[i] = c ? atomicAdd(&bcur[i], c) : 0;
    hist[i] = 0;
  }
  __syncthreads();
  for (int r = threadIdx.x; r < cnt; r += 256) {
    int d = dst[t0 + r];
    int s = src[t0 + r];
    int b = d >> NBSHIFT;
    int off = atomicAdd(&hist[b], 1);
    bin[base[b] + off] = ((unsigned)(d & 255) << 17) | (unsigned)s;
  }
}

__global__ __launch_bounds__(256) void k_fillB(
    const unsigned* __restrict__ bin, const int* __restrict__ cb,
    int* __restrict__ rp, int* __restrict__ ssrc, int n, int E) {
  __shared__ int deg[256];
  __shared__ int ts[256];
  __shared__ int cur[256];
  int b = blockIdx.x;
  int nbase = b << NBSHIFT;
  int nn = min(256, n - nbase);
  int ebeg = cb[b], eend = cb[b + 1];
  deg[threadIdx.x] = 0;
  __syncthreads();
  for (int e = ebeg + (int)threadIdx.x; e < eend; e += 256)
    atomicAdd(&deg[bin[e] >> 17], 1);
  __syncthreads();
  int d = deg[threadIdx.x];
  ts[threadIdx.x] = d;
  __syncthreads();
  for (int off = 1; off < 256; off <<= 1) {
    int val = (threadIdx.x >= off) ? ts[threadIdx.x - off] : 0;
    __syncthreads();
    ts[threadIdx.x] += val;
    __syncthreads();
  }
  int pref = ts[threadIdx.x] - d;
  if ((int)threadIdx.x < nn) {
    rp[nbase + threadIdx.x] = ebeg + pref;
    cur[threadIdx.x] = ebeg + pref;
  }
  if (b == 0 && threadIdx.x == 0) rp[n] = E;
  __syncthreads();
  for (int e = ebeg + (int)threadIdx.x; e < eend; e += 256) {
    unsigned u = bin[e];
    int dlow = (int)(u >> 17);
    int s = (int)(u & 0x1FFFF);
    int pos = atomicAdd(&cur[dlow], 1);
    ssrc[pos] = s;
  }
}

// ===================== fp32 x -> fp16 into F1[node][0..31] =====================

__global__ __launch_bounds__(256) void k_tohalf(
    const float2* __restrict__ in, __half2* __restrict__ f1, int n2) {
  int i = blockIdx.x * 256 + threadIdx.x;
  if (i >= n2) return;
  float2 v = in[i];
  int node = i >> 4, f2 = i & 15;
  f1[(size_t)node * 32 + f2] = __floats2half2_rn(v.x, v.y);
}

// ===================== gather segment sums (fp16) =====================
// 1<<LOGG half2-lanes per node; feat rows LDH2 half2 wide, read at OFFR,
// write half2 at row stride LDH2, offset OFFW.
template<int LOGG, int LDH2, int OFFR, int OFFW>
__global__ __launch_bounds__(256) void k_gather(
    const __half2* __restrict__ feat, const int* __restrict__ rp,
    const int* __restrict__ ssrc, __half2* __restrict__ outp, int n) {
  int t = blockIdx.x * 256 + threadIdx.x;
  int node = t >> LOGG;
  int f2 = t & ((1 << LOGG) - 1);
  if (node >= n) return;
  int beg = rp[node], end = rp[node + 1];
  float ax = 0.f, ay = 0.f;
  int e = beg;
  for (; e + 3 < end; e += 4) {
    int s0 = ssrc[e];
    int s1 = ssrc[e + 1];
    int s2 = ssrc[e + 2];
    int s3 = ssrc[e + 3];
    float2 v0 = __half22float2(feat[(size_t)s0 * LDH2 + OFFR + f2]);
    float2 v1 = __half22float2(feat[(size_t)s1 * LDH2 + OFFR + f2]);
    float2 v2 = __half22float2(feat[(size_t)s2 * LDH2 + OFFR + f2]);
    float2 v3 = __half22float2(feat[(size_t)s3 * LDH2 + OFFR + f2]);
    ax += v0.x; ay += v0.y;
    ax += v1.x; ay += v1.y;
    ax += v2.x; ay += v2.y;
    ax += v3.x; ay += v3.y;
  }
  for (; e < end; ++e) {
    float2 v = __half22float2(feat[(size_t)ssrc[e] * LDH2 + OFFR + f2]);
    ax += v.x; ay += v.y;
  }
  outp[(size_t)node * LDH2 + OFFW + f2] = __floats2half2_rn(ax, ay);
}

// ===================== weight fragment prep =====================
// A-frag mapping (16x16x32): out=16*mt+(lane&15), k = 32*kt + (lane>>4)*8 + j.

// W1: F1=[x|agg1] -> k<32: w1_root[k][out], k>=32: w1_rel[k-32][out]. 512 frag-slots.
__global__ __launch_bounds__(256) void k_prepw1(
    const float* __restrict__ w_rel, const float* __restrict__ w_root,
    __half* __restrict__ wf) {
  int u = blockIdx.x * 256 + threadIdx.x;   // [0,512): mt(2b) kt(1b) lane(6b)
  if (u >= 512) return;
  int lane = u & 63, kt = (u >> 6) & 1, mt = u >> 7;
  int out = 16 * mt + (lane & 15);
  int kb = 32 * kt + (lane >> 4) * 8;
  union { uint4 q; __half h[8]; } pk;
#pragma unroll
  for (int j = 0; j < 8; ++j) {
    int k = kb + j;
    float w = (k < 32) ? w_root[k * DH + out] : w_rel[(k - 32) * DH + out];
    pk.h[j] = __float2half(w);
  }
  *(uint4*)(wf + (size_t)u * 8) = pk.q;
}

// W2: F2=[agg2|h1] -> k<64: w2_rel[k][out], k>=64: w2_root[k-64][out]. 1024 slots.
__global__ __launch_bounds__(256) void k_prepw2(
    const float* __restrict__ w_rel, const float* __restrict__ w_root,
    __half* __restrict__ wf) {
  int u = blockIdx.x * 256 + threadIdx.x;   // [0,1024): mt(2b) kt(2b) lane(6b)
  if (u >= 1024) return;
  int lane = u & 63, kt = (u >> 6) & 3, mt = u >> 8;
  int out = 16 * mt + (lane & 15);
  int kb = 32 * kt + (lane >> 4) * 8;
  union { uint4 q; __half h[8]; } pk;
#pragma unroll
  for (int j = 0; j < 8; ++j) {
    int k = kb + j;
    float w = (k < 64) ? w_rel[k * DH + out] : w_root[(k - 64) * DH + out];
    pk.h[j] = __float2half(w);
  }
  *(uint4*)(wf + (size_t)u * 8) = pk.q;
}

// ===================== layer 1 (MFMA) =====================
// h1 = relu([x|agg1] @ [w1_root;w1_rel] + b1) -> fp16 into F2[node][64..127]
__global__ __launch_bounds__(256) void k_l1mfma(
    const _Float16* __restrict__ F1, const _Float16* __restrict__ WF,
    const float* __restrict__ b1, _Float16* __restrict__ F2, int n) {
  int lane = threadIdx.x & 63;
  int wv = (blockIdx.x * 256 + threadIdx.x) >> 6;
  int nb = wv * 16;
  if (nb >= n) return;
  int node = nb + (lane & 15);
  int nodeld = min(node, n - 1);
  const _Float16* fp = F1 + (size_t)nodeld * 64 + (lane >> 4) * 8;
  f16x8 bf[2];
#pragma unroll
  for (int kt = 0; kt < 2; ++kt) bf[kt] = *(const f16x8*)(fp + kt * 32);
  const f16x8* ap = (const f16x8*)WF + lane;
  f32x4 acc[4];
#pragma unroll
  for (int mt = 0; mt < 4; ++mt) acc[mt] = (f32x4)(0.f);
#pragma unroll
  for (int mt = 0; mt < 4; ++mt)
#pragma unroll
    for (int kt = 0; kt < 2; ++kt)
      acc[mt] = __builtin_amdgcn_mfma_f32_16x16x32_f16(
          ap[(mt * 2 + kt) * 64], bf[kt], acc[mt], 0, 0, 0);
  if (node >= n) return;
  int jb = (lane >> 4) * 4;
  _Float16* op = F2 + (size_t)node * 128 + 64 + jb;
#pragma unroll
  for (int mt = 0; mt < 4; ++mt) {
    f32x4 vb = *(const f32x4*)(b1 + 16 * mt + jb);
    union { uint2 u; _Float16 h[4]; } pk;
#pragma unroll
    for (int r = 0; r < 4; ++r)
      pk.h[r] = (_Float16)fmaxf(acc[mt][r] + vb[r], 0.f);
    *(uint2*)(op + 16 * mt) = pk.u;
  }
}

// ===================== layer 2 (MFMA) =====================
__global__ __launch_bounds__(256) void k_l2mfma(
    const _Float16* __restrict__ F2, const _Float16* __restrict__ WF,
    const float* __restrict__ b2, const float* __restrict__ w3rel,
    const float* __restrict__ w3root,
    float* __restrict__ S, float* __restrict__ T, int n) {
  int lane = threadIdx.x & 63;
  int wv = (blockIdx.x * 256 + threadIdx.x) >> 6;
  int nb = wv * 16;
  if (nb >= n) return;
  int node = nb + (lane & 15);
  int nodeld = min(node, n - 1);
  const _Float16* fp = F2 + (size_t)nodeld * 128 + (lane >> 4) * 8;
  f16x8 bf[4];
#pragma unroll
  for (int kt = 0; kt < 4; ++kt) bf[kt] = *(const f16x8*)(fp + kt * 32);
  const f16x8* ap = (const f16x8*)WF + lane;
  f32x4 acc[4];
#pragma unroll
  for (int mt = 0; mt < 4; ++mt) acc[mt] = (f32x4)(0.f);
#pragma unroll
  for (int mt = 0; mt < 4; ++mt)
#pragma unroll
    for (int kt = 0; kt < 4; ++kt)
      acc[mt] = __builtin_amdgcn_mfma_f32_16x16x32_f16(
          ap[(mt * 4 + kt) * 64], bf[kt], acc[mt], 0, 0, 0);
  int jb = (lane >> 4) * 4;
  float s = 0.f, t = 0.f;
#pragma unroll
  for (int mt = 0; mt < 4; ++mt) {
    f32x4 vb = *(const f32x4*)(b2 + 16 * mt + jb);
    f32x4 vr = *(const f32x4*)(w3rel + 16 * mt + jb);
    f32x4 vt = *(const f32x4*)(w3root + 16 * mt + jb);
#pragma unroll
    for (int r = 0; r < 4; ++r) {
      float h = fmaxf(acc[mt][r] + vb[r], 0.f);
      s = fmaf(h, vr[r], s);
      t = fmaf(h, vt[r], t);
    }
  }
  s += __shfl_xor(s, 16); s += __shfl_xor(s, 32);
  t += __shfl_xor(t, 16); t += __shfl_xor(t, 32);
  if (lane < 16 && node < n) { S[node] = s; T[node] = t; }
}

// ===================== final: out = segsum(S) + b3 + T =====================

__global__ __launch_bounds__(256) void k_final(
    const float* __restrict__ sv, const int* __restrict__ rp,
    const int* __restrict__ ssrc, const float* __restrict__ T,
    const float* __restrict__ b3, float* __restrict__ out, int n) {
  int i = blockIdx.x * 256 + threadIdx.x;
  if (i >= n) return;
  int beg = rp[i], end = rp[i + 1];
  float a = b3[0] + T[i];
  int e = beg;
  for (; e + 3 < end; e += 4) {
    float v0 = sv[ssrc[e]];
    float v1 = sv[ssrc[e + 1]];
    float v2 = sv[ssrc[e + 2]];
    float v3 = sv[ssrc[e + 3]];
    a += v0; a += v1; a += v2; a += v3;
  }
  for (; e < end; ++e) a += sv[ssrc[e]];
  out[i] = a;
}

// ===================== launch =====================

extern "C" void kernel_launch(void* const* d_in, const int* in_sizes, int n_in,
                              void* d_out, int out_size, void* d_ws, size_t ws_size,
                              hipStream_t stream) {
  const float* x       = (const float*)d_in[0];
  const float* w1_rel  = (const float*)d_in[1];
  const float* b1      = (const float*)d_in[2];
  const float* w1_root = (const float*)d_in[3];
  const float* w2_rel  = (const float*)d_in[4];
  const float* b2      = (const float*)d_in[5];
  const float* w2_root = (const float*)d_in[6];
  const float* w3_rel  = (const float*)d_in[7];
  const float* b3      = (const float*)d_in[8];
  const float* w3_root = (const float*)d_in[9];
  const int*   edge    = (const int*)d_in[10];

  const int n = in_sizes[0] / DIN;        // 100000 (< 2^17 for packing)
  const int E = in_sizes[10] / 2;         // 1600000
  const int* src = edge;
  const int* dst = edge + E;

  _Float16* F1 = (_Float16*)d_ws;                     // n*64 halfs [x|agg1]
  _Float16* F2 = F1 + (size_t)n * 64;                 // n*128 halfs [agg2|h1]
  float*    S  = (float*)(F2 + (size_t)n * 128);      // n
  float*    T  = S + n;                               // n
  int* RP   = (int*)(T + n);                          // n+1 (pad to 8)
  int* SSRC = RP + ((n + 8) & ~7);                    // E
  int* CH   = SSRC + E;                               // 512 coarse counts
  int* CB   = CH + 512;                               // 513 coarse bases
  int* BCUR = CB + 520;                               // 512 cursors
  __half* WF1 = (__half*)(BCUR + 512);                // 4096 halfs
  __half* WF2 = WF1 + 4096;                           // 8192 halfs
  unsigned* BIN = (unsigned*)F2;                      // E (dead before F2 writes)

  const int B = 256;
  const int gn = (n + B - 1) / B;
  const int nbuckets = (n + 255) >> NBSHIFT;          // 391
  const int gA = (E + TILE_A - 1) / TILE_A;           // 391

  // ---- CSR build ----
  hipMemsetAsync(CH, 0, 512 * sizeof(int), stream);
  k_chist<<<gA, B, 0, stream>>>(dst, CH, E, nbuckets);
  k_cscan<<<1, B, 0, stream>>>(CH, CB, BCUR, nbuckets, E);
  k_binA<<<gA, B, 0, stream>>>(src, dst, BCUR, BIN, E, nbuckets);
  k_fillB<<<nbuckets, B, 0, stream>>>(BIN, CB, RP, SSRC, n, E);

  // ---- weight prep + x->fp16 ----
  k_prepw1<<<2, B, 0, stream>>>(w1_rel, w1_root, WF1);
  k_prepw2<<<4, B, 0, stream>>>(w2_rel, w2_root, WF2);
  {
    int n2 = n * (DIN / 2);
    k_tohalf<<<(n2 + B - 1) / B, B, 0, stream>>>((const float2*)x, (__half2*)F1, n2);
  }

  // ---- layer 1 ---- (gather x -> agg1 into F1[32..63]; MFMA -> h1 into F2[64..127])
  {
    long long tot = (long long)n * 16;
    k_gather<4, 32, 0, 16><<<(unsigned)((tot + B - 1) / B), B, 0, stream>>>(
        (const __half2*)F1, RP, SSRC, (__half2*)F1, n);
  }
  {
    int waves = (n + 15) / 16;
    int blocks = (waves + 3) / 4;
    k_l1mfma<<<blocks, B, 0, stream>>>(F1, (const _Float16*)WF1, b1, F2, n);
  }

  // ---- layer 2 ---- (gather h1 -> agg2 into F2[0..63]; MFMA)
  {
    long long tot = (long long)n * 32;
    k_gather<5, 64, 32, 0><<<(unsigned)((tot + B - 1) / B), B, 0, stream>>>(
        (const __half2*)F2, RP, SSRC, (__half2*)F2, n);
  }
  {
    int waves = (n + 15) / 16;
    int blocks = (waves + 3) / 4;
    k_l2mfma<<<blocks, B, 0, stream>>>(F2, (const _Float16*)WF2,
                                       b2, w3_rel, w3_root, S, T, n);
  }

  // ---- layer 3 ----
  k_final<<<gn, B, 0, stream>>>(S, RP, SSRC, T, b3, (float*)d_out, n);
}

// Round 10
// 164.965 us; speedup vs baseline: 2.0232x; 1.0929x over previous
//
#include <hip/hip_runtime.h>
#include <hip/hip_fp16.h>

typedef _Float16 f16x8 __attribute__((ext_vector_type(8)));
typedef float    f32x4 __attribute__((ext_vector_type(4)));

constexpr int DIN = 32;
constexpr int DH  = 64;
constexpr int NBSHIFT = 8;            // 256 nodes per coarse bucket
constexpr int TILE_A  = 4096;         // edges per phase-A block (391 blocks)

// ===================== CSR build (coarse-first two-level sort) ==============

__global__ __launch_bounds__(256) void k_zero512(int* __restrict__ p) {
  p[threadIdx.x] = 0;
  p[256 + threadIdx.x] = 0;
}

__global__ __launch_bounds__(256) void k_chist(
    const int* __restrict__ dst, int* __restrict__ ch, int E, int nbuckets) {
  __shared__ int hist[512];
  long long t0 = (long long)blockIdx.x * TILE_A;
  int cnt = (int)min((long long)TILE_A, (long long)E - t0);
  for (int i = threadIdx.x; i < nbuckets; i += 256) hist[i] = 0;
  __syncthreads();
  for (int r = threadIdx.x; r < cnt; r += 256)
    atomicAdd(&hist[dst[t0 + r] >> NBSHIFT], 1);
  __syncthreads();
  for (int i = threadIdx.x; i < nbuckets; i += 256)
    if (hist[i]) atomicAdd(&ch[i], hist[i]);
}

__global__ __launch_bounds__(256) void k_cscan(
    const int* __restrict__ ch, int* __restrict__ cb, int* __restrict__ bcur,
    int nbuckets, int E) {
  __shared__ int ts[256];
  int i0 = threadIdx.x * 2, i1 = i0 + 1;
  int v0 = (i0 < nbuckets) ? ch[i0] : 0;
  int v1 = (i1 < nbuckets) ? ch[i1] : 0;
  int s = v0 + v1;
  ts[threadIdx.x] = s;
  __syncthreads();
  for (int off = 1; off < 256; off <<= 1) {
    int val = (threadIdx.x >= off) ? ts[threadIdx.x - off] : 0;
    __syncthreads();
    ts[threadIdx.x] += val;
    __syncthreads();
  }
  int ex = ts[threadIdx.x] - s;
  if (i0 < nbuckets) { cb[i0] = ex;      bcur[i0] = ex; }
  if (i1 < nbuckets) { cb[i1] = ex + v0; bcur[i1] = ex + v0; }
  if (threadIdx.x == 255) cb[nbuckets] = E;
}

__global__ __launch_bounds__(256) void k_binA(
    const int* __restrict__ src, const int* __restrict__ dst,
    int* __restrict__ bcur, unsigned* __restrict__ bin,
    int E, int nbuckets) {
  __shared__ int hist[512];
  __shared__ int base[512];
  long long t0 = (long long)blockIdx.x * TILE_A;
  int cnt = (int)min((long long)TILE_A, (long long)E - t0);
  for (int i = threadIdx.x; i < nbuckets; i += 256) hist[i] = 0;
  __syncthreads();
  for (int r = threadIdx.x; r < cnt; r += 256)
    atomicAdd(&hist[dst[t0 + r] >> NBSHIFT], 1);
  __syncthreads();
  for (int i = threadIdx.x; i < nbuckets; i += 256) {
    int c = hist[i];
    base[i] = c ? atomicAdd(&bcur[i], c) : 0;
    hist[i] = 0;
  }
  __syncthreads();
  for (int r = threadIdx.x; r < cnt; r += 256) {
    int d = dst[t0 + r];
    int s = src[t0 + r];
    int b = d >> NBSHIFT;
    int off = atomicAdd(&hist[b], 1);
    bin[base[b] + off] = ((unsigned)(d & 255) << 17) | (unsigned)s;
  }
}

__global__ __launch_bounds__(256) void k_fillB(
    const unsigned* __restrict__ bin, const int* __restrict__ cb,
    int* __restrict__ rp, int* __restrict__ ssrc, int n, int E) {
  __shared__ int deg[256];
  __shared__ int ts[256];
  __shared__ int cur[256];
  int b = blockIdx.x;
  int nbase = b << NBSHIFT;
  int nn = min(256, n - nbase);
  int ebeg = cb[b], eend = cb[b + 1];
  deg[threadIdx.x] = 0;
  __syncthreads();
  for (int e = ebeg + (int)threadIdx.x; e < eend; e += 256)
    atomicAdd(&deg[bin[e] >> 17], 1);
  __syncthreads();
  int d = deg[threadIdx.x];
  ts[threadIdx.x] = d;
  __syncthreads();
  for (int off = 1; off < 256; off <<= 1) {
    int val = (threadIdx.x >= off) ? ts[threadIdx.x - off] : 0;
    __syncthreads();
    ts[threadIdx.x] += val;
    __syncthreads();
  }
  int pref = ts[threadIdx.x] - d;
  if ((int)threadIdx.x < nn) {
    rp[nbase + threadIdx.x] = ebeg + pref;
    cur[threadIdx.x] = ebeg + pref;
  }
  if (b == 0 && threadIdx.x == 0) rp[n] = E;
  __syncthreads();
  for (int e = ebeg + (int)threadIdx.x; e < eend; e += 256) {
    unsigned u = bin[e];
    int dlow = (int)(u >> 17);
    int s = (int)(u & 0x1FFFF);
    int pos = atomicAdd(&cur[dlow], 1);
    ssrc[pos] = s;
  }
}

// ===================== fp32 x -> fp16 into F1[node][0..31] =====================

__global__ __launch_bounds__(256) void k_tohalf(
    const float2* __restrict__ in, __half2* __restrict__ f1, int n2) {
  int i = blockIdx.x * 256 + threadIdx.x;
  if (i >= n2) return;
  float2 v = in[i];
  int node = i >> 4, f2 = i & 15;
  f1[(size_t)node * 32 + f2] = __floats2half2_rn(v.x, v.y);
}

// ===================== gather segment sums (fp16, 16B/lane) =====================
// 1<<LOGG lanes per node, each lane covers 8 halfs (16 B).
// feat rows are LDH8 x 16B units; read at unit OFFR8, write at unit OFFW8.
template<int LOGG, int LDH8, int OFFR8, int OFFW8>
__global__ __launch_bounds__(256) void k_gather(
    const f16x8* __restrict__ feat, const int* __restrict__ rp,
    const int* __restrict__ ssrc, f16x8* __restrict__ outp, int n) {
  int t = blockIdx.x * 256 + threadIdx.x;
  int node = t >> LOGG;
  int f8 = t & ((1 << LOGG) - 1);
  if (node >= n) return;
  int beg = rp[node], end = rp[node + 1];
  float acc[8];
#pragma unroll
  for (int j = 0; j < 8; ++j) acc[j] = 0.f;
  int e = beg;
  for (; e + 3 < end; e += 4) {
    int s0 = ssrc[e];
    int s1 = ssrc[e + 1];
    int s2 = ssrc[e + 2];
    int s3 = ssrc[e + 3];
    f16x8 v0 = feat[(size_t)s0 * LDH8 + OFFR8 + f8];
    f16x8 v1 = feat[(size_t)s1 * LDH8 + OFFR8 + f8];
    f16x8 v2 = feat[(size_t)s2 * LDH8 + OFFR8 + f8];
    f16x8 v3 = feat[(size_t)s3 * LDH8 + OFFR8 + f8];
#pragma unroll
    for (int j = 0; j < 8; ++j) {
      acc[j] += (float)v0[j];
      acc[j] += (float)v1[j];
      acc[j] += (float)v2[j];
      acc[j] += (float)v3[j];
    }
  }
  for (; e < end; ++e) {
    f16x8 v = feat[(size_t)ssrc[e] * LDH8 + OFFR8 + f8];
#pragma unroll
    for (int j = 0; j < 8; ++j) acc[j] += (float)v[j];
  }
  f16x8 r;
#pragma unroll
  for (int j = 0; j < 8; ++j) r[j] = (_Float16)acc[j];
  outp[(size_t)node * LDH8 + OFFW8 + f8] = r;
}

// ===================== weight fragment prep =====================
// A-frag mapping (16x16x32): out=16*mt+(lane&15), k = 32*kt + (lane>>4)*8 + j.

__global__ __launch_bounds__(256) void k_prepw1(
    const float* __restrict__ w_rel, const float* __restrict__ w_root,
    __half* __restrict__ wf) {
  int u = blockIdx.x * 256 + threadIdx.x;   // [0,512): mt(2b) kt(1b) lane(6b)
  if (u >= 512) return;
  int lane = u & 63, kt = (u >> 6) & 1, mt = u >> 7;
  int out = 16 * mt + (lane & 15);
  int kb = 32 * kt + (lane >> 4) * 8;
  union { uint4 q; __half h[8]; } pk;
#pragma unroll
  for (int j = 0; j < 8; ++j) {
    int k = kb + j;
    float w = (k < 32) ? w_root[k * DH + out] : w_rel[(k - 32) * DH + out];
    pk.h[j] = __float2half(w);
  }
  *(uint4*)(wf + (size_t)u * 8) = pk.q;
}

__global__ __launch_bounds__(256) void k_prepw2(
    const float* __restrict__ w_rel, const float* __restrict__ w_root,
    __half* __restrict__ wf) {
  int u = blockIdx.x * 256 + threadIdx.x;   // [0,1024): mt(2b) kt(2b) lane(6b)
  if (u >= 1024) return;
  int lane = u & 63, kt = (u >> 6) & 3, mt = u >> 8;
  int out = 16 * mt + (lane & 15);
  int kb = 32 * kt + (lane >> 4) * 8;
  union { uint4 q; __half h[8]; } pk;
#pragma unroll
  for (int j = 0; j < 8; ++j) {
    int k = kb + j;
    float w = (k < 64) ? w_rel[k * DH + out] : w_root[(k - 64) * DH + out];
    pk.h[j] = __float2half(w);
  }
  *(uint4*)(wf + (size_t)u * 8) = pk.q;
}

// ===================== layer 1 (MFMA) =====================
// h1 = relu([x|agg1] @ [w1_root;w1_rel] + b1) -> fp16 into F2[node][64..127]
__global__ __launch_bounds__(256) void k_l1mfma(
    const _Float16* __restrict__ F1, const _Float16* __restrict__ WF,
    const float* __restrict__ b1, _Float16* __restrict__ F2, int n) {
  int lane = threadIdx.x & 63;
  int wv = (blockIdx.x * 256 + threadIdx.x) >> 6;
  int nb = wv * 16;
  if (nb >= n) return;
  int node = nb + (lane & 15);
  int nodeld = min(node, n - 1);
  const _Float16* fp = F1 + (size_t)nodeld * 64 + (lane >> 4) * 8;
  f16x8 bf[2];
#pragma unroll
  for (int kt = 0; kt < 2; ++kt) bf[kt] = *(const f16x8*)(fp + kt * 32);
  const f16x8* ap = (const f16x8*)WF + lane;
  f32x4 acc[4];
#pragma unroll
  for (int mt = 0; mt < 4; ++mt) acc[mt] = (f32x4)(0.f);
#pragma unroll
  for (int mt = 0; mt < 4; ++mt)
#pragma unroll
    for (int kt = 0; kt < 2; ++kt)
      acc[mt] = __builtin_amdgcn_mfma_f32_16x16x32_f16(
          ap[(mt * 2 + kt) * 64], bf[kt], acc[mt], 0, 0, 0);
  if (node >= n) return;
  int jb = (lane >> 4) * 4;
  _Float16* op = F2 + (size_t)node * 128 + 64 + jb;
#pragma unroll
  for (int mt = 0; mt < 4; ++mt) {
    f32x4 vb = *(const f32x4*)(b1 + 16 * mt + jb);
    union { uint2 u; _Float16 h[4]; } pk;
#pragma unroll
    for (int r = 0; r < 4; ++r)
      pk.h[r] = (_Float16)fmaxf(acc[mt][r] + vb[r], 0.f);
    *(uint2*)(op + 16 * mt) = pk.u;
  }
}

// ===================== layer 2 (MFMA) =====================
__global__ __launch_bounds__(256) void k_l2mfma(
    const _Float16* __restrict__ F2, const _Float16* __restrict__ WF,
    const float* __restrict__ b2, const float* __restrict__ w3rel,
    const float* __restrict__ w3root,
    float* __restrict__ S, float* __restrict__ T, int n) {
  int lane = threadIdx.x & 63;
  int wv = (blockIdx.x * 256 + threadIdx.x) >> 6;
  int nb = wv * 16;
  if (nb >= n) return;
  int node = nb + (lane & 15);
  int nodeld = min(node, n - 1);
  const _Float16* fp = F2 + (size_t)nodeld * 128 + (lane >> 4) * 8;
  f16x8 bf[4];
#pragma unroll
  for (int kt = 0; kt < 4; ++kt) bf[kt] = *(const f16x8*)(fp + kt * 32);
  const f16x8* ap = (const f16x8*)WF + lane;
  f32x4 acc[4];
#pragma unroll
  for (int mt = 0; mt < 4; ++mt) acc[mt] = (f32x4)(0.f);
#pragma unroll
  for (int mt = 0; mt < 4; ++mt)
#pragma unroll
    for (int kt = 0; kt < 4; ++kt)
      acc[mt] = __builtin_amdgcn_mfma_f32_16x16x32_f16(
          ap[(mt * 4 + kt) * 64], bf[kt], acc[mt], 0, 0, 0);
  int jb = (lane >> 4) * 4;
  float s = 0.f, t = 0.f;
#pragma unroll
  for (int mt = 0; mt < 4; ++mt) {
    f32x4 vb = *(const f32x4*)(b2 + 16 * mt + jb);
    f32x4 vr = *(const f32x4*)(w3rel + 16 * mt + jb);
    f32x4 vt = *(const f32x4*)(w3root + 16 * mt + jb);
#pragma unroll
    for (int r = 0; r < 4; ++r) {
      float h = fmaxf(acc[mt][r] + vb[r], 0.f);
      s = fmaf(h, vr[r], s);
      t = fmaf(h, vt[r], t);
    }
  }
  s += __shfl_xor(s, 16); s += __shfl_xor(s, 32);
  t += __shfl_xor(t, 16); t += __shfl_xor(t, 32);
  if (lane < 16 && node < n) { S[node] = s; T[node] = t; }
}

// ===================== final: out = segsum(S) + b3 + T (4 lanes/node) =======

__global__ __launch_bounds__(256) void k_final(
    const float* __restrict__ sv, const int* __restrict__ rp,
    const int* __restrict__ ssrc, const float* __restrict__ T,
    const float* __restrict__ b3, float* __restrict__ out, int n) {
  int t = blockIdx.x * 256 + threadIdx.x;
  int node = t >> 2;
  int l = t & 3;
  if (node >= n) return;
  int beg = rp[node], end = rp[node + 1];
  float a = 0.f;
  for (int e = beg + l; e < end; e += 4) a += sv[ssrc[e]];
  a += __shfl_xor(a, 1);
  a += __shfl_xor(a, 2);
  if (l == 0) out[node] = a + b3[0] + T[node];
}

// ===================== launch =====================

extern "C" void kernel_launch(void* const* d_in, const int* in_sizes, int n_in,
                              void* d_out, int out_size, void* d_ws, size_t ws_size,
                              hipStream_t stream) {
  const float* x       = (const float*)d_in[0];
  const float* w1_rel  = (const float*)d_in[1];
  const float* b1      = (const float*)d_in[2];
  const float* w1_root = (const float*)d_in[3];
  const float* w2_rel  = (const float*)d_in[4];
  const float* b2      = (const float*)d_in[5];
  const float* w2_root = (const float*)d_in[6];
  const float* w3_rel  = (const float*)d_in[7];
  const float* b3      = (const float*)d_in[8];
  const float* w3_root = (const float*)d_in[9];
  const int*   edge    = (const int*)d_in[10];

  const int n = in_sizes[0] / DIN;        // 100000 (< 2^17 for packing)
  const int E = in_sizes[10] / 2;         // 1600000
  const int* src = edge;
  const int* dst = edge + E;

  _Float16* F1 = (_Float16*)d_ws;                     // n*64 halfs [x|agg1]
  _Float16* F2 = F1 + (size_t)n * 64;                 // n*128 halfs [agg2|h1]
  float*    S  = (float*)(F2 + (size_t)n * 128);      // n
  float*    T  = S + n;                               // n
  int* RP   = (int*)(T + n);                          // n+1 (pad to 8)
  int* SSRC = RP + ((n + 8) & ~7);                    // E
  int* CH   = SSRC + E;                               // 512 coarse counts
  int* CB   = CH + 512;                               // 513 coarse bases
  int* BCUR = CB + 520;                               // 512 cursors
  __half* WF1 = (__half*)(BCUR + 512);                // 4096 halfs
  __half* WF2 = WF1 + 4096;                           // 8192 halfs
  unsigned* BIN = (unsigned*)F2;                      // E (dead before F2 writes)

  const int B = 256;
  const int nbuckets = (n + 255) >> NBSHIFT;          // 391
  const int gA = (E + TILE_A - 1) / TILE_A;           // 391

  // ---- CSR build ----
  k_zero512<<<1, B, 0, stream>>>(CH);
  k_chist<<<gA, B, 0, stream>>>(dst, CH, E, nbuckets);
  k_cscan<<<1, B, 0, stream>>>(CH, CB, BCUR, nbuckets, E);
  k_binA<<<gA, B, 0, stream>>>(src, dst, BCUR, BIN, E, nbuckets);
  k_fillB<<<nbuckets, B, 0, stream>>>(BIN, CB, RP, SSRC, n, E);

  // ---- weight prep + x->fp16 ----
  k_prepw1<<<2, B, 0, stream>>>(w1_rel, w1_root, WF1);
  k_prepw2<<<4, B, 0, stream>>>(w2_rel, w2_root, WF2);
  {
    int n2 = n * (DIN / 2);
    k_tohalf<<<(n2 + B - 1) / B, B, 0, stream>>>((const float2*)x, (__half2*)F1, n2);
  }

  // ---- layer 1 ---- (gather x -> agg1 into F1 units 4..7; MFMA -> h1 into F2)
  {
    long long tot = (long long)n << 2;     // 4 lanes/node
    k_gather<2, 8, 0, 4><<<(unsigned)((tot + B - 1) / B), B, 0, stream>>>(
        (const f16x8*)F1, RP, SSRC, (f16x8*)F1, n);
  }
  {
    int waves = (n + 15) / 16;
    int blocks = (waves + 3) / 4;
    k_l1mfma<<<blocks, B, 0, stream>>>(F1, (const _Float16*)WF1, b1, F2, n);
  }

  // ---- layer 2 ---- (gather h1 (units 8..15) -> agg2 into F2 units 0..7; MFMA)
  {
    long long tot = (long long)n << 3;     // 8 lanes/node
    k_gather<3, 16, 8, 0><<<(unsigned)((tot + B - 1) / B), B, 0, stream>>>(
        (const f16x8*)F2, RP, SSRC, (f16x8*)F2, n);
  }
  {
    int waves = (n + 15) / 16;
    int blocks = (waves + 3) / 4;
    k_l2mfma<<<blocks, B, 0, stream>>>(F2, (const _Float16*)WF2,
                                       b2, w3_rel, w3_root, S, T, n);
  }

  // ---- layer 3 ----
  k_final<<<(4 * n + B - 1) / B, B, 0, stream>>>(S, RP, SSRC, T, b3, (float*)d_out, n);
}

// Round 11
// 142.954 us; speedup vs baseline: 2.3347x; 1.1540x over previous
//
#include <hip/hip_runtime.h>
#include <hip/hip_fp16.h>

typedef _Float16 f16x8 __attribute__((ext_vector_type(8)));
typedef float    f32x4 __attribute__((ext_vector_type(4)));

constexpr int DIN = 32;
constexpr int DH  = 64;
constexpr int NBSHIFT = 8;            // 256 nodes per coarse bucket
constexpr int TILE_A  = 4096;         // edges per phase-A block
constexpr int FB_CAP  = 6144;         // fillB LDS sort capacity (avg segment ~4096)

// ===================== fused setup: x->fp16, weight frags, zero CH ==========

__global__ __launch_bounds__(256) void k_setup(
    const float2* __restrict__ x2, __half2* __restrict__ xh,
    const float* __restrict__ w1_rel, const float* __restrict__ w1_root,
    const float* __restrict__ w2_rel, const float* __restrict__ w2_root,
    __half* __restrict__ wf1, __half* __restrict__ wf2,
    int* __restrict__ ch, int n2) {
  int i = blockIdx.x * 256 + threadIdx.x;
  if (i < n2) {                       // x (n x 32 f32) -> fp16 rows
    float2 v = x2[i];
    xh[i] = __floats2half2_rn(v.x, v.y);
    return;
  }
  int u = i - n2;
  if (u < 512) {                      // W1 A-frags: k<32 w1_root, k>=32 w1_rel
    int lane = u & 63, kt = (u >> 6) & 1, mt = u >> 7;
    int out = 16 * mt + (lane & 15);
    int kb = 32 * kt + (lane >> 4) * 8;
    union { uint4 q; __half h[8]; } pk;
#pragma unroll
    for (int j = 0; j < 8; ++j) {
      int k = kb + j;
      float w = (k < 32) ? w1_root[k * DH + out] : w1_rel[(k - 32) * DH + out];
      pk.h[j] = __float2half(w);
    }
    *(uint4*)(wf1 + (size_t)u * 8) = pk.q;
    return;
  }
  u -= 512;
  if (u < 1024) {                     // W2 A-frags: k<64 w2_rel, k>=64 w2_root
    int lane = u & 63, kt = (u >> 6) & 3, mt = u >> 8;
    int out = 16 * mt + (lane & 15);
    int kb = 32 * kt + (lane >> 4) * 8;
    union { uint4 q; __half h[8]; } pk;
#pragma unroll
    for (int j = 0; j < 8; ++j) {
      int k = kb + j;
      float w = (k < 64) ? w2_rel[k * DH + out] : w2_root[(k - 64) * DH + out];
      pk.h[j] = __float2half(w);
    }
    *(uint4*)(wf2 + (size_t)u * 8) = pk.q;
    return;
  }
  u -= 1024;
  if (u < 512) ch[u] = 0;
}

// ===================== CSR build =====================

__global__ __launch_bounds__(256) void k_chist(
    const int* __restrict__ dst, int* __restrict__ ch, int E, int nbuckets) {
  __shared__ int hist[512];
  long long t0 = (long long)blockIdx.x * TILE_A;
  int cnt = (int)min((long long)TILE_A, (long long)E - t0);
  for (int i = threadIdx.x; i < nbuckets; i += 256) hist[i] = 0;
  __syncthreads();
  for (int r = threadIdx.x; r < cnt; r += 256)
    atomicAdd(&hist[dst[t0 + r] >> NBSHIFT], 1);
  __syncthreads();
  for (int i = threadIdx.x; i < nbuckets; i += 256)
    if (hist[i]) atomicAdd(&ch[i], hist[i]);
}

__global__ __launch_bounds__(256) void k_cscan(
    const int* __restrict__ ch, int* __restrict__ cb, int* __restrict__ bcur,
    int nbuckets, int E) {
  __shared__ int ts[256];
  int i0 = threadIdx.x * 2, i1 = i0 + 1;
  int v0 = (i0 < nbuckets) ? ch[i0] : 0;
  int v1 = (i1 < nbuckets) ? ch[i1] : 0;
  int s = v0 + v1;
  ts[threadIdx.x] = s;
  __syncthreads();
  for (int off = 1; off < 256; off <<= 1) {
    int val = (threadIdx.x >= off) ? ts[threadIdx.x - off] : 0;
    __syncthreads();
    ts[threadIdx.x] += val;
    __syncthreads();
  }
  int ex = ts[threadIdx.x] - s;
  if (i0 < nbuckets) { cb[i0] = ex;      bcur[i0] = ex; }
  if (i1 < nbuckets) { cb[i1] = ex + v0; bcur[i1] = ex + v0; }
  if (threadIdx.x == 255) cb[nbuckets] = E;
}

// Phase A: bin edges into coarse buckets; LDS-sorted so global writes are
// bucket-grouped runs instead of fully scattered 4B stores.
__global__ __launch_bounds__(256) void k_binA(
    const int* __restrict__ src, const int* __restrict__ dst,
    int* __restrict__ bcur, unsigned* __restrict__ bin,
    int E, int nbuckets) {
  __shared__ int hist[512];
  __shared__ int lbase[512];
  __shared__ int gbase[512];
  __shared__ int ts[256];
  __shared__ unsigned lsort[TILE_A];
  __shared__ unsigned short lbuck[TILE_A];
  long long t0 = (long long)blockIdx.x * TILE_A;
  int cnt = (int)min((long long)TILE_A, (long long)E - t0);
  for (int i = threadIdx.x; i < 512; i += 256) hist[i] = 0;
  __syncthreads();
  unsigned pk[TILE_A / 256];          // static-indexed (rule #20)
  int bo[TILE_A / 256];
#pragma unroll
  for (int q = 0; q < TILE_A / 256; ++q) {
    int r = (int)threadIdx.x + q * 256;
    if (r < cnt) {
      int d = dst[t0 + r];
      int s = src[t0 + r];
      int b = d >> NBSHIFT;
      int off = atomicAdd(&hist[b], 1);
      pk[q] = ((unsigned)(d & 255) << 17) | (unsigned)s;
      bo[q] = (b << 16) | off;
    }
  }
  __syncthreads();
  {                                   // scan hist -> lbase; reserve gbase
    int i0 = threadIdx.x * 2, i1 = i0 + 1;
    int v0 = hist[i0], v1 = hist[i1];
    int s2 = v0 + v1;
    ts[threadIdx.x] = s2;
    __syncthreads();
    for (int off = 1; off < 256; off <<= 1) {
      int val = (threadIdx.x >= off) ? ts[threadIdx.x - off] : 0;
      __syncthreads();
      ts[threadIdx.x] += val;
      __syncthreads();
    }
    int ex = ts[threadIdx.x] - s2;
    lbase[i0] = ex;
    lbase[i1] = ex + v0;
    gbase[i0] = v0 ? atomicAdd(&bcur[i0], v0) : 0;
    gbase[i1] = v1 ? atomicAdd(&bcur[i1], v1) : 0;
  }
  __syncthreads();
#pragma unroll
  for (int q = 0; q < TILE_A / 256; ++q) {
    int r = (int)threadIdx.x + q * 256;
    if (r < cnt) {
      int b = bo[q] >> 16, off = bo[q] & 0xFFFF;
      int li = lbase[b] + off;
      lsort[li] = pk[q];
      lbuck[li] = (unsigned short)b;
    }
  }
  __syncthreads();
  for (int i = threadIdx.x; i < cnt; i += 256) {
    int b = lbuck[i];
    bin[gbase[b] + (i - lbase[b])] = lsort[i];
  }
}

// Phase B: fine counting sort per bucket; ssrc written fully coalesced via LDS.
__global__ __launch_bounds__(256) void k_fillB(
    const unsigned* __restrict__ bin, const int* __restrict__ cb,
    int* __restrict__ rp, int* __restrict__ ssrc, int n, int E) {
  __shared__ int deg[256];
  __shared__ int ts[256];
  __shared__ int cur[256];
  __shared__ int lsort[FB_CAP];
  int b = blockIdx.x;
  int nbase = b << NBSHIFT;
  int nn = min(256, n - nbase);
  int ebeg = cb[b], eend = cb[b + 1];
  int cnt = eend - ebeg;
  deg[threadIdx.x] = 0;
  __syncthreads();
  for (int e = ebeg + (int)threadIdx.x; e < eend; e += 256)
    atomicAdd(&deg[bin[e] >> 17], 1);
  __syncthreads();
  int d = deg[threadIdx.x];
  ts[threadIdx.x] = d;
  __syncthreads();
  for (int off = 1; off < 256; off <<= 1) {
    int val = (threadIdx.x >= off) ? ts[threadIdx.x - off] : 0;
    __syncthreads();
    ts[threadIdx.x] += val;
    __syncthreads();
  }
  int pref = ts[threadIdx.x] - d;
  if ((int)threadIdx.x < nn) rp[nbase + threadIdx.x] = ebeg + pref;
  if (b == 0 && threadIdx.x == 0) rp[n] = E;
  cur[threadIdx.x] = pref;            // intra-segment cursor
  __syncthreads();
  if (cnt <= FB_CAP) {
    for (int e = ebeg + (int)threadIdx.x; e < eend; e += 256) {
      unsigned u = bin[e];
      int pos = atomicAdd(&cur[u >> 17], 1);
      lsort[pos] = (int)(u & 0x1FFFF);
    }
    __syncthreads();
    for (int i = threadIdx.x; i < cnt; i += 256)
      ssrc[ebeg + i] = lsort[i];      // coalesced
  } else {                            // pathological skew fallback
    for (int e = ebeg + (int)threadIdx.x; e < eend; e += 256) {
      unsigned u = bin[e];
      int pos = atomicAdd(&cur[u >> 17], 1);
      ssrc[ebeg + pos] = (int)(u & 0x1FFFF);
    }
  }
}

// ===================== layer 1 fused: gather(LDS) + MFMA =====================
// h1 = relu([x|agg1] @ [w1_root;w1_rel] + b1) -> fp16 H1[node][0..63]
__global__ __launch_bounds__(256) void k_l1fused(
    const _Float16* __restrict__ X, const int* __restrict__ rp,
    const int* __restrict__ ssrc, const _Float16* __restrict__ WF,
    const float* __restrict__ b1, _Float16* __restrict__ H1, int n) {
  __shared__ _Float16 sagg[64][40];   // 32 halfs + pad->40 (2-way max)
  int tid = threadIdx.x;
  int nl = tid >> 2;
  int unit = tid & 3;
  int nodeg = blockIdx.x * 64 + nl;
  {
    float acc[8];
#pragma unroll
    for (int j = 0; j < 8; ++j) acc[j] = 0.f;
    if (nodeg < n) {
      int beg = rp[nodeg], end = rp[nodeg + 1];
      const f16x8* fx = (const f16x8*)X;
      int e = beg;
      for (; e + 3 < end; e += 4) {
        int s0 = ssrc[e], s1 = ssrc[e + 1], s2 = ssrc[e + 2], s3 = ssrc[e + 3];
        f16x8 v0 = fx[(size_t)s0 * 4 + unit];
        f16x8 v1 = fx[(size_t)s1 * 4 + unit];
        f16x8 v2 = fx[(size_t)s2 * 4 + unit];
        f16x8 v3 = fx[(size_t)s3 * 4 + unit];
#pragma unroll
        for (int j = 0; j < 8; ++j) {
          acc[j] += (float)v0[j]; acc[j] += (float)v1[j];
          acc[j] += (float)v2[j]; acc[j] += (float)v3[j];
        }
      }
      for (; e < end; ++e) {
        f16x8 v = fx[(size_t)ssrc[e] * 4 + unit];
#pragma unroll
        for (int j = 0; j < 8; ++j) acc[j] += (float)v[j];
      }
    }
    f16x8 r;
#pragma unroll
    for (int j = 0; j < 8; ++j) r[j] = (_Float16)acc[j];
    *(f16x8*)&sagg[nl][unit * 8] = r;
  }
  __syncthreads();
  int lane = tid & 63;
  int w = tid >> 6;
  int nl16 = w * 16 + (lane & 15);
  int node = blockIdx.x * 64 + nl16;
  int nodeld = min(node, n - 1);
  f16x8 bf0 = *(const f16x8*)(X + (size_t)nodeld * 32 + (lane >> 4) * 8);
  f16x8 bf1 = *(const f16x8*)&sagg[nl16][(lane >> 4) * 8];
  const f16x8* ap = (const f16x8*)WF + lane;
  f32x4 acc[4];
#pragma unroll
  for (int mt = 0; mt < 4; ++mt) acc[mt] = (f32x4)(0.f);
#pragma unroll
  for (int mt = 0; mt < 4; ++mt) {
    acc[mt] = __builtin_amdgcn_mfma_f32_16x16x32_f16(ap[(mt * 2 + 0) * 64], bf0, acc[mt], 0, 0, 0);
    acc[mt] = __builtin_amdgcn_mfma_f32_16x16x32_f16(ap[(mt * 2 + 1) * 64], bf1, acc[mt], 0, 0, 0);
  }
  if (node >= n) return;
  int jb = (lane >> 4) * 4;
  _Float16* op = H1 + (size_t)node * 64 + jb;
#pragma unroll
  for (int mt = 0; mt < 4; ++mt) {
    f32x4 vb = *(const f32x4*)(b1 + 16 * mt + jb);
    union { uint2 u2; _Float16 h[4]; } pko;
#pragma unroll
    for (int r = 0; r < 4; ++r)
      pko.h[r] = (_Float16)fmaxf(acc[mt][r] + vb[r], 0.f);
    *(uint2*)(op + 16 * mt) = pko.u2;
  }
}

// ===================== layer 2 fused: gather(LDS) + MFMA + proj =============
// h2 = relu([agg2|h1] @ [w2_rel;w2_root] + b2); S=h2@w3_rel, T=h2@w3_root
__global__ __launch_bounds__(256) void k_l2fused(
    const _Float16* __restrict__ H1, const int* __restrict__ rp,
    const int* __restrict__ ssrc, const _Float16* __restrict__ WF,
    const float* __restrict__ b2, const float* __restrict__ w3rel,
    const float* __restrict__ w3root,
    float* __restrict__ S, float* __restrict__ T, int n) {
  __shared__ _Float16 sagg[64][72];   // 64 halfs + pad->72 (2-way max)
  int tid = threadIdx.x;
  int nl = tid >> 2;
  int u0 = tid & 3;                   // this lane covers units u0 and u0+4
  int nodeg = blockIdx.x * 64 + nl;
  {
    float acc[16];
#pragma unroll
    for (int j = 0; j < 16; ++j) acc[j] = 0.f;
    if (nodeg < n) {
      int beg = rp[nodeg], end = rp[nodeg + 1];
      const f16x8* fh = (const f16x8*)H1;
      int e = beg;
      for (; e + 1 < end; e += 2) {
        int s0 = ssrc[e], s1 = ssrc[e + 1];
        f16x8 a0 = fh[(size_t)s0 * 8 + u0];
        f16x8 c0 = fh[(size_t)s0 * 8 + u0 + 4];
        f16x8 a1 = fh[(size_t)s1 * 8 + u0];
        f16x8 c1 = fh[(size_t)s1 * 8 + u0 + 4];
#pragma unroll
        for (int j = 0; j < 8; ++j) {
          acc[j] += (float)a0[j];     acc[j] += (float)a1[j];
          acc[8 + j] += (float)c0[j]; acc[8 + j] += (float)c1[j];
        }
      }
      for (; e < end; ++e) {
        int s0 = ssrc[e];
        f16x8 a0 = fh[(size_t)s0 * 8 + u0];
        f16x8 c0 = fh[(size_t)s0 * 8 + u0 + 4];
#pragma unroll
        for (int j = 0; j < 8; ++j) {
          acc[j] += (float)a0[j];
          acc[8 + j] += (float)c0[j];
        }
      }
    }
    f16x8 r0, r1;
#pragma unroll
    for (int j = 0; j < 8; ++j) {
      r0[j] = (_Float16)acc[j];
      r1[j] = (_Float16)acc[8 + j];
    }
    *(f16x8*)&sagg[nl][u0 * 8] = r0;
    *(f16x8*)&sagg[nl][(u0 + 4) * 8] = r1;
  }
  __syncthreads();
  int lane = tid & 63;
  int w = tid >> 6;
  int nl16 = w * 16 + (lane & 15);
  int node = blockIdx.x * 64 + nl16;
  int nodeld = min(node, n - 1);
  f16x8 bf[4];
  bf[0] = *(const f16x8*)&sagg[nl16][(lane >> 4) * 8];
  bf[1] = *(const f16x8*)&sagg[nl16][32 + (lane >> 4) * 8];
  bf[2] = *(const f16x8*)(H1 + (size_t)nodeld * 64 + (lane >> 4) * 8);
  bf[3] = *(const f16x8*)(H1 + (size_t)nodeld * 64 + 32 + (lane >> 4) * 8);
  const f16x8* ap = (const f16x8*)WF + lane;
  f32x4 acc[4];
#pragma unroll
  for (int mt = 0; mt < 4; ++mt) acc[mt] = (f32x4)(0.f);
#pragma unroll
  for (int mt = 0; mt < 4; ++mt)
#pragma unroll
    for (int kt = 0; kt < 4; ++kt)
      acc[mt] = __builtin_amdgcn_mfma_f32_16x16x32_f16(
          ap[(mt * 4 + kt) * 64], bf[kt], acc[mt], 0, 0, 0);
  int jb = (lane >> 4) * 4;
  float s = 0.f, t = 0.f;
#pragma unroll
  for (int mt = 0; mt < 4; ++mt) {
    f32x4 vb = *(const f32x4*)(b2 + 16 * mt + jb);
    f32x4 vr = *(const f32x4*)(w3rel + 16 * mt + jb);
    f32x4 vt = *(const f32x4*)(w3root + 16 * mt + jb);
#pragma unroll
    for (int r = 0; r < 4; ++r) {
      float h = fmaxf(acc[mt][r] + vb[r], 0.f);
      s = fmaf(h, vr[r], s);
      t = fmaf(h, vt[r], t);
    }
  }
  s += __shfl_xor(s, 16); s += __shfl_xor(s, 32);
  t += __shfl_xor(t, 16); t += __shfl_xor(t, 32);
  if (lane < 16 && node < n) { S[node] = s; T[node] = t; }
}

// ===================== final: out = segsum(S) + b3 + T (4 lanes/node) =======

__global__ __launch_bounds__(256) void k_final(
    const float* __restrict__ sv, const int* __restrict__ rp,
    const int* __restrict__ ssrc, const float* __restrict__ T,
    const float* __restrict__ b3, float* __restrict__ out, int n) {
  int t = blockIdx.x * 256 + threadIdx.x;
  int node = t >> 2;
  int l = t & 3;
  if (node >= n) return;
  int beg = rp[node], end = rp[node + 1];
  float a = 0.f;
  for (int e = beg + l; e < end; e += 4) a += sv[ssrc[e]];
  a += __shfl_xor(a, 1);
  a += __shfl_xor(a, 2);
  if (l == 0) out[node] = a + b3[0] + T[node];
}

// ===================== launch =====================

extern "C" void kernel_launch(void* const* d_in, const int* in_sizes, int n_in,
                              void* d_out, int out_size, void* d_ws, size_t ws_size,
                              hipStream_t stream) {
  const float* x       = (const float*)d_in[0];
  const float* w1_rel  = (const float*)d_in[1];
  const float* b1      = (const float*)d_in[2];
  const float* w1_root = (const float*)d_in[3];
  const float* w2_rel  = (const float*)d_in[4];
  const float* b2      = (const float*)d_in[5];
  const float* w2_root = (const float*)d_in[6];
  const float* w3_rel  = (const float*)d_in[7];
  const float* b3      = (const float*)d_in[8];
  const float* w3_root = (const float*)d_in[9];
  const int*   edge    = (const int*)d_in[10];

  const int n = in_sizes[0] / DIN;        // 100000 (< 2^17 for packing)
  const int E = in_sizes[10] / 2;         // 1600000
  const int* src = edge;
  const int* dst = edge + E;

  _Float16* XH = (_Float16*)d_ws;                     // n*32 halfs (x fp16)
  _Float16* H1 = XH + (size_t)n * 32;                 // n*64 halfs (h1)
  float*    S  = (float*)(H1 + (size_t)n * 64);       // n
  float*    T  = S + n;                               // n
  int* RP   = (int*)(T + n);                          // n+1 (pad to 8)
  int* SSRC = RP + ((n + 8) & ~7);                    // E
  int* CH   = SSRC + E;                               // 512
  int* CB   = CH + 512;                               // 513 (pad 520)
  int* BCUR = CB + 520;                               // 512
  __half* WF1 = (__half*)(BCUR + 512);                // 4096 halfs
  __half* WF2 = WF1 + 4096;                           // 8192 halfs
  unsigned* BIN = (unsigned*)H1;                      // E (dead before H1 writes)

  const int B = 256;
  const int nbuckets = (n + 255) >> NBSHIFT;          // 391
  const int gA = (E + TILE_A - 1) / TILE_A;           // 391
  const int gF = (n + 63) / 64;                       // fused-layer blocks

  // setup: x->fp16 | W1 frags | W2 frags | zero CH   (one kernel)
  {
    int n2 = n * 16;
    int tot = n2 + 2048;
    k_setup<<<(tot + B - 1) / B, B, 0, stream>>>(
        (const float2*)x, (__half2*)XH, w1_rel, w1_root, w2_rel, w2_root,
        WF1, WF2, CH, n2);
  }

  // CSR build
  k_chist<<<gA, B, 0, stream>>>(dst, CH, E, nbuckets);
  k_cscan<<<1, B, 0, stream>>>(CH, CB, BCUR, nbuckets, E);
  k_binA<<<gA, B, 0, stream>>>(src, dst, BCUR, BIN, E, nbuckets);
  k_fillB<<<nbuckets, B, 0, stream>>>(BIN, CB, RP, SSRC, n, E);

  // layers (gather fused with MFMA; agg lives only in LDS)
  k_l1fused<<<gF, B, 0, stream>>>(XH, RP, SSRC, (const _Float16*)WF1, b1, H1, n);
  k_l2fused<<<gF, B, 0, stream>>>(H1, RP, SSRC, (const _Float16*)WF2,
                                  b2, w3_rel, w3_root, S, T, n);

  // layer 3
  k_final<<<(4 * n + B - 1) / B, B, 0, stream>>>(S, RP, SSRC, T, b3, (float*)d_out, n);
}

// Round 12
// 139.711 us; speedup vs baseline: 2.3889x; 1.0232x over previous
//
#include <hip/hip_runtime.h>
#include <hip/hip_fp16.h>

typedef _Float16 f16x8 __attribute__((ext_vector_type(8)));
typedef float    f32x4 __attribute__((ext_vector_type(4)));

constexpr int DIN = 32;
constexpr int DH  = 64;
constexpr int NBSHIFT = 8;            // 256 nodes per coarse bucket
constexpr int TILE_A  = 4096;         // edges per phase-A block
constexpr int FB_CAP  = 6144;         // fillB LDS sort capacity

// ===================== fused setup: x->fp16, weight frags, zero CH ==========

__global__ __launch_bounds__(256) void k_setup(
    const float2* __restrict__ x2, __half2* __restrict__ xh,
    const float* __restrict__ w1_rel, const float* __restrict__ w1_root,
    const float* __restrict__ w2_rel, const float* __restrict__ w2_root,
    __half* __restrict__ wf1, __half* __restrict__ wf2,
    int* __restrict__ ch, int n2) {
  int i = blockIdx.x * 256 + threadIdx.x;
  if (i < n2) {
    float2 v = x2[i];
    xh[i] = __floats2half2_rn(v.x, v.y);
    return;
  }
  int u = i - n2;
  if (u < 512) {                      // W1 A-frags: k<32 w1_root, k>=32 w1_rel
    int lane = u & 63, kt = (u >> 6) & 1, mt = u >> 7;
    int out = 16 * mt + (lane & 15);
    int kb = 32 * kt + (lane >> 4) * 8;
    union { uint4 q; __half h[8]; } pk;
#pragma unroll
    for (int j = 0; j < 8; ++j) {
      int k = kb + j;
      float w = (k < 32) ? w1_root[k * DH + out] : w1_rel[(k - 32) * DH + out];
      pk.h[j] = __float2half(w);
    }
    *(uint4*)(wf1 + (size_t)u * 8) = pk.q;
    return;
  }
  u -= 512;
  if (u < 1024) {                     // W2 A-frags: k<64 w2_rel, k>=64 w2_root
    int lane = u & 63, kt = (u >> 6) & 3, mt = u >> 8;
    int out = 16 * mt + (lane & 15);
    int kb = 32 * kt + (lane >> 4) * 8;
    union { uint4 q; __half h[8]; } pk;
#pragma unroll
    for (int j = 0; j < 8; ++j) {
      int k = kb + j;
      float w = (k < 64) ? w2_rel[k * DH + out] : w2_root[(k - 64) * DH + out];
      pk.h[j] = __float2half(w);
    }
    *(uint4*)(wf2 + (size_t)u * 8) = pk.q;
    return;
  }
  u -= 1024;
  if (u < 512) ch[u] = 0;
}

// ===================== CSR build =====================

__global__ __launch_bounds__(256) void k_chist(
    const int* __restrict__ dst, int* __restrict__ ch, int E, int nbuckets) {
  __shared__ int hist[512];
  long long t0 = (long long)blockIdx.x * TILE_A;
  int cnt = (int)min((long long)TILE_A, (long long)E - t0);
  for (int i = threadIdx.x; i < nbuckets; i += 256) hist[i] = 0;
  __syncthreads();
  for (int r = threadIdx.x; r < cnt; r += 256)
    atomicAdd(&hist[dst[t0 + r] >> NBSHIFT], 1);
  __syncthreads();
  for (int i = threadIdx.x; i < nbuckets; i += 256)
    if (hist[i]) atomicAdd(&ch[i], hist[i]);
}

__global__ __launch_bounds__(256) void k_cscan(
    const int* __restrict__ ch, int* __restrict__ cb, int* __restrict__ bcur,
    int nbuckets, int E) {
  __shared__ int ts[256];
  int i0 = threadIdx.x * 2, i1 = i0 + 1;
  int v0 = (i0 < nbuckets) ? ch[i0] : 0;
  int v1 = (i1 < nbuckets) ? ch[i1] : 0;
  int s = v0 + v1;
  ts[threadIdx.x] = s;
  __syncthreads();
  for (int off = 1; off < 256; off <<= 1) {
    int val = (threadIdx.x >= off) ? ts[threadIdx.x - off] : 0;
    __syncthreads();
    ts[threadIdx.x] += val;
    __syncthreads();
  }
  int ex = ts[threadIdx.x] - s;
  if (i0 < nbuckets) { cb[i0] = ex;      bcur[i0] = ex; }
  if (i1 < nbuckets) { cb[i1] = ex + v0; bcur[i1] = ex + v0; }
  if (threadIdx.x == 255) cb[nbuckets] = E;
}

// Phase A: bin edges into coarse buckets; LDS-sorted -> bucket-grouped writes.
__global__ __launch_bounds__(256) void k_binA(
    const int* __restrict__ src, const int* __restrict__ dst,
    int* __restrict__ bcur, unsigned* __restrict__ bin,
    int E, int nbuckets) {
  __shared__ int hist[512];
  __shared__ int lbase[512];
  __shared__ int gbase[512];
  __shared__ int ts[256];
  __shared__ unsigned lsort[TILE_A];
  __shared__ unsigned short lbuck[TILE_A];
  long long t0 = (long long)blockIdx.x * TILE_A;
  int cnt = (int)min((long long)TILE_A, (long long)E - t0);
  for (int i = threadIdx.x; i < 512; i += 256) hist[i] = 0;
  __syncthreads();
  unsigned pk[TILE_A / 256];
  int bo[TILE_A / 256];
#pragma unroll
  for (int q = 0; q < TILE_A / 256; ++q) {
    int r = (int)threadIdx.x + q * 256;
    if (r < cnt) {
      int d = dst[t0 + r];
      int s = src[t0 + r];
      int b = d >> NBSHIFT;
      int off = atomicAdd(&hist[b], 1);
      pk[q] = ((unsigned)(d & 255) << 17) | (unsigned)s;
      bo[q] = (b << 16) | off;
    }
  }
  __syncthreads();
  {
    int i0 = threadIdx.x * 2, i1 = i0 + 1;
    int v0 = hist[i0], v1 = hist[i1];
    int s2 = v0 + v1;
    ts[threadIdx.x] = s2;
    __syncthreads();
    for (int off = 1; off < 256; off <<= 1) {
      int val = (threadIdx.x >= off) ? ts[threadIdx.x - off] : 0;
      __syncthreads();
      ts[threadIdx.x] += val;
      __syncthreads();
    }
    int ex = ts[threadIdx.x] - s2;
    lbase[i0] = ex;
    lbase[i1] = ex + v0;
    gbase[i0] = v0 ? atomicAdd(&bcur[i0], v0) : 0;
    gbase[i1] = v1 ? atomicAdd(&bcur[i1], v1) : 0;
  }
  __syncthreads();
#pragma unroll
  for (int q = 0; q < TILE_A / 256; ++q) {
    int r = (int)threadIdx.x + q * 256;
    if (r < cnt) {
      int b = bo[q] >> 16, off = bo[q] & 0xFFFF;
      int li = lbase[b] + off;
      lsort[li] = pk[q];
      lbuck[li] = (unsigned short)b;
    }
  }
  __syncthreads();
  for (int i = threadIdx.x; i < cnt; i += 256) {
    int b = lbuck[i];
    bin[gbase[b] + (i - lbase[b])] = lsort[i];
  }
}

// Phase B: fine counting sort per bucket; coalesced ssrc writes via LDS.
__global__ __launch_bounds__(256) void k_fillB(
    const unsigned* __restrict__ bin, const int* __restrict__ cb,
    int* __restrict__ rp, int* __restrict__ ssrc, int n, int E) {
  __shared__ int deg[256];
  __shared__ int ts[256];
  __shared__ int cur[256];
  __shared__ int lsort[FB_CAP];
  int b = blockIdx.x;
  int nbase = b << NBSHIFT;
  int nn = min(256, n - nbase);
  int ebeg = cb[b], eend = cb[b + 1];
  int cnt = eend - ebeg;
  deg[threadIdx.x] = 0;
  __syncthreads();
  for (int e = ebeg + (int)threadIdx.x; e < eend; e += 256)
    atomicAdd(&deg[bin[e] >> 17], 1);
  __syncthreads();
  int d = deg[threadIdx.x];
  ts[threadIdx.x] = d;
  __syncthreads();
  for (int off = 1; off < 256; off <<= 1) {
    int val = (threadIdx.x >= off) ? ts[threadIdx.x - off] : 0;
    __syncthreads();
    ts[threadIdx.x] += val;
    __syncthreads();
  }
  int pref = ts[threadIdx.x] - d;
  if ((int)threadIdx.x < nn) rp[nbase + threadIdx.x] = ebeg + pref;
  if (b == 0 && threadIdx.x == 0) rp[n] = E;
  cur[threadIdx.x] = pref;
  __syncthreads();
  if (cnt <= FB_CAP) {
    for (int e = ebeg + (int)threadIdx.x; e < eend; e += 256) {
      unsigned u = bin[e];
      int pos = atomicAdd(&cur[u >> 17], 1);
      lsort[pos] = (int)(u & 0x1FFFF);
    }
    __syncthreads();
    for (int i = threadIdx.x; i < cnt; i += 256)
      ssrc[ebeg + i] = lsort[i];
  } else {
    for (int e = ebeg + (int)threadIdx.x; e < eend; e += 256) {
      unsigned u = bin[e];
      int pos = atomicAdd(&cur[u >> 17], 1);
      ssrc[ebeg + pos] = (int)(u & 0x1FFFF);
    }
  }
}

// ===================== layer 1 fused: gather(LDS) + MFMA =====================
// h1 = relu([x|agg1] @ [w1_root;w1_rel] + b1) -> fp16 H1[node][0..63]
// Gather accumulates in packed fp16 (v_pk_add_f16): 4x less VALU per edge.
__global__ __launch_bounds__(256) void k_l1fused(
    const _Float16* __restrict__ X, const int* __restrict__ rp,
    const int* __restrict__ ssrc, const _Float16* __restrict__ WF,
    const float* __restrict__ b1, _Float16* __restrict__ H1, int n) {
  __shared__ _Float16 sagg[64][40];
  int tid = threadIdx.x;
  int nl = tid >> 2;
  int unit = tid & 3;
  int nodeg = blockIdx.x * 64 + nl;
  {
    f16x8 accA = (f16x8)(_Float16)0.0f;
    f16x8 accB = (f16x8)(_Float16)0.0f;
    if (nodeg < n) {
      int beg = rp[nodeg], end = rp[nodeg + 1];
      const f16x8* fx = (const f16x8*)X;
      int e = beg;
      for (; e + 3 < end; e += 4) {
        int s0 = ssrc[e], s1 = ssrc[e + 1], s2 = ssrc[e + 2], s3 = ssrc[e + 3];
        f16x8 v0 = fx[(size_t)s0 * 4 + unit];
        f16x8 v1 = fx[(size_t)s1 * 4 + unit];
        f16x8 v2 = fx[(size_t)s2 * 4 + unit];
        f16x8 v3 = fx[(size_t)s3 * 4 + unit];
        accA += v0; accB += v1; accA += v2; accB += v3;
      }
      for (; e < end; ++e) accA += fx[(size_t)ssrc[e] * 4 + unit];
    }
    *(f16x8*)&sagg[nl][unit * 8] = accA + accB;
  }
  __syncthreads();
  int lane = tid & 63;
  int w = tid >> 6;
  int nl16 = w * 16 + (lane & 15);
  int node = blockIdx.x * 64 + nl16;
  int nodeld = min(node, n - 1);
  f16x8 bf0 = *(const f16x8*)(X + (size_t)nodeld * 32 + (lane >> 4) * 8);
  f16x8 bf1 = *(const f16x8*)&sagg[nl16][(lane >> 4) * 8];
  const f16x8* ap = (const f16x8*)WF + lane;
  f32x4 acc[4];
#pragma unroll
  for (int mt = 0; mt < 4; ++mt) acc[mt] = (f32x4)(0.f);
#pragma unroll
  for (int mt = 0; mt < 4; ++mt) {
    acc[mt] = __builtin_amdgcn_mfma_f32_16x16x32_f16(ap[(mt * 2 + 0) * 64], bf0, acc[mt], 0, 0, 0);
    acc[mt] = __builtin_amdgcn_mfma_f32_16x16x32_f16(ap[(mt * 2 + 1) * 64], bf1, acc[mt], 0, 0, 0);
  }
  if (node >= n) return;
  int jb = (lane >> 4) * 4;
  _Float16* op = H1 + (size_t)node * 64 + jb;
#pragma unroll
  for (int mt = 0; mt < 4; ++mt) {
    f32x4 vb = *(const f32x4*)(b1 + 16 * mt + jb);
    union { uint2 u2; _Float16 h[4]; } pko;
#pragma unroll
    for (int r = 0; r < 4; ++r)
      pko.h[r] = (_Float16)fmaxf(acc[mt][r] + vb[r], 0.f);
    *(uint2*)(op + 16 * mt) = pko.u2;
  }
}

// ===================== layer 2 fused: gather(LDS) + MFMA + proj =============
// h2 = relu([agg2|h1] @ [w2_rel;w2_root] + b2); S=h2@w3_rel, T=h2@w3_root
__global__ __launch_bounds__(256) void k_l2fused(
    const _Float16* __restrict__ H1, const int* __restrict__ rp,
    const int* __restrict__ ssrc, const _Float16* __restrict__ WF,
    const float* __restrict__ b2, const float* __restrict__ w3rel,
    const float* __restrict__ w3root,
    float* __restrict__ S, float* __restrict__ T, int n) {
  __shared__ _Float16 sagg[64][72];
  int tid = threadIdx.x;
  int nl = tid >> 2;
  int u0 = tid & 3;                   // lane covers units u0 and u0+4
  int nodeg = blockIdx.x * 64 + nl;
  {
    f16x8 aA = (f16x8)(_Float16)0.0f, aB = (f16x8)(_Float16)0.0f;
    f16x8 cA = (f16x8)(_Float16)0.0f, cB = (f16x8)(_Float16)0.0f;
    if (nodeg < n) {
      int beg = rp[nodeg], end = rp[nodeg + 1];
      const f16x8* fh = (const f16x8*)H1;
      int e = beg;
      for (; e + 3 < end; e += 4) {
        int s0 = ssrc[e], s1 = ssrc[e + 1], s2 = ssrc[e + 2], s3 = ssrc[e + 3];
        f16x8 a0 = fh[(size_t)s0 * 8 + u0];
        f16x8 c0 = fh[(size_t)s0 * 8 + u0 + 4];
        f16x8 a1 = fh[(size_t)s1 * 8 + u0];
        f16x8 c1 = fh[(size_t)s1 * 8 + u0 + 4];
        f16x8 a2 = fh[(size_t)s2 * 8 + u0];
        f16x8 c2 = fh[(size_t)s2 * 8 + u0 + 4];
        f16x8 a3 = fh[(size_t)s3 * 8 + u0];
        f16x8 c3 = fh[(size_t)s3 * 8 + u0 + 4];
        aA += a0; cA += c0; aB += a1; cB += c1;
        aA += a2; cA += c2; aB += a3; cB += c3;
      }
      for (; e < end; ++e) {
        int s0 = ssrc[e];
        aA += fh[(size_t)s0 * 8 + u0];
        cA += fh[(size_t)s0 * 8 + u0 + 4];
      }
    }
    *(f16x8*)&sagg[nl][u0 * 8] = aA + aB;
    *(f16x8*)&sagg[nl][(u0 + 4) * 8] = cA + cB;
  }
  __syncthreads();
  int lane = tid & 63;
  int w = tid >> 6;
  int nl16 = w * 16 + (lane & 15);
  int node = blockIdx.x * 64 + nl16;
  int nodeld = min(node, n - 1);
  f16x8 bf[4];
  bf[0] = *(const f16x8*)&sagg[nl16][(lane >> 4) * 8];
  bf[1] = *(const f16x8*)&sagg[nl16][32 + (lane >> 4) * 8];
  bf[2] = *(const f16x8*)(H1 + (size_t)nodeld * 64 + (lane >> 4) * 8);
  bf[3] = *(const f16x8*)(H1 + (size_t)nodeld * 64 + 32 + (lane >> 4) * 8);
  const f16x8* ap = (const f16x8*)WF + lane;
  f32x4 acc[4];
#pragma unroll
  for (int mt = 0; mt < 4; ++mt) acc[mt] = (f32x4)(0.f);
#pragma unroll
  for (int mt = 0; mt < 4; ++mt)
#pragma unroll
    for (int kt = 0; kt < 4; ++kt)
      acc[mt] = __builtin_amdgcn_mfma_f32_16x16x32_f16(
          ap[(mt * 4 + kt) * 64], bf[kt], acc[mt], 0, 0, 0);
  int jb = (lane >> 4) * 4;
  float s = 0.f, t = 0.f;
#pragma unroll
  for (int mt = 0; mt < 4; ++mt) {
    f32x4 vb = *(const f32x4*)(b2 + 16 * mt + jb);
    f32x4 vr = *(const f32x4*)(w3rel + 16 * mt + jb);
    f32x4 vt = *(const f32x4*)(w3root + 16 * mt + jb);
#pragma unroll
    for (int r = 0; r < 4; ++r) {
      float h = fmaxf(acc[mt][r] + vb[r], 0.f);
      s = fmaf(h, vr[r], s);
      t = fmaf(h, vt[r], t);
    }
  }
  s += __shfl_xor(s, 16); s += __shfl_xor(s, 32);
  t += __shfl_xor(t, 16); t += __shfl_xor(t, 32);
  if (lane < 16 && node < n) { S[node] = s; T[node] = t; }
}

// ===================== final: out = segsum(S) + b3 + T (4 lanes/node) =======

__global__ __launch_bounds__(256) void k_final(
    const float* __restrict__ sv, const int* __restrict__ rp,
    const int* __restrict__ ssrc, const float* __restrict__ T,
    const float* __restrict__ b3, float* __restrict__ out, int n) {
  int t = blockIdx.x * 256 + threadIdx.x;
  int node = t >> 2;
  int l = t & 3;
  if (node >= n) return;
  int beg = rp[node], end = rp[node + 1];
  float a = 0.f;
  for (int e = beg + l; e < end; e += 4) a += sv[ssrc[e]];
  a += __shfl_xor(a, 1);
  a += __shfl_xor(a, 2);
  if (l == 0) out[node] = a + b3[0] + T[node];
}

// ===================== launch =====================

extern "C" void kernel_launch(void* const* d_in, const int* in_sizes, int n_in,
                              void* d_out, int out_size, void* d_ws, size_t ws_size,
                              hipStream_t stream) {
  const float* x       = (const float*)d_in[0];
  const float* w1_rel  = (const float*)d_in[1];
  const float* b1      = (const float*)d_in[2];
  const float* w1_root = (const float*)d_in[3];
  const float* w2_rel  = (const float*)d_in[4];
  const float* b2      = (const float*)d_in[5];
  const float* w2_root = (const float*)d_in[6];
  const float* w3_rel  = (const float*)d_in[7];
  const float* b3      = (const float*)d_in[8];
  const float* w3_root = (const float*)d_in[9];
  const int*   edge    = (const int*)d_in[10];

  const int n = in_sizes[0] / DIN;        // 100000 (< 2^17 for packing)
  const int E = in_sizes[10] / 2;         // 1600000
  const int* src = edge;
  const int* dst = edge + E;

  _Float16* XH = (_Float16*)d_ws;                     // n*32 halfs (x fp16)
  _Float16* H1 = XH + (size_t)n * 32;                 // n*64 halfs (h1)
  float*    S  = (float*)(H1 + (size_t)n * 64);       // n
  float*    T  = S + n;                               // n
  int* RP   = (int*)(T + n);                          // n+1 (pad to 8)
  int* SSRC = RP + ((n + 8) & ~7);                    // E
  int* CH   = SSRC + E;                               // 512
  int* CB   = CH + 512;                               // 513 (pad 520)
  int* BCUR = CB + 520;                               // 512
  __half* WF1 = (__half*)(BCUR + 512);                // 4096 halfs
  __half* WF2 = WF1 + 4096;                           // 8192 halfs
  unsigned* BIN = (unsigned*)H1;                      // E (dead before H1 writes)

  const int B = 256;
  const int nbuckets = (n + 255) >> NBSHIFT;          // 391
  const int gA = (E + TILE_A - 1) / TILE_A;           // 391
  const int gF = (n + 63) / 64;                       // fused-layer blocks

  // setup: x->fp16 | W1 frags | W2 frags | zero CH
  {
    int n2 = n * 16;
    int tot = n2 + 2048;
    k_setup<<<(tot + B - 1) / B, B, 0, stream>>>(
        (const float2*)x, (__half2*)XH, w1_rel, w1_root, w2_rel, w2_root,
        WF1, WF2, CH, n2);
  }

  // CSR build
  k_chist<<<gA, B, 0, stream>>>(dst, CH, E, nbuckets);
  k_cscan<<<1, B, 0, stream>>>(CH, CB, BCUR, nbuckets, E);
  k_binA<<<gA, B, 0, stream>>>(src, dst, BCUR, BIN, E, nbuckets);
  k_fillB<<<nbuckets, B, 0, stream>>>(BIN, CB, RP, SSRC, n, E);

  // layers (gather fused with MFMA; agg in LDS, packed-fp16 accumulate)
  k_l1fused<<<gF, B, 0, stream>>>(XH, RP, SSRC, (const _Float16*)WF1, b1, H1, n);
  k_l2fused<<<gF, B, 0, stream>>>(H1, RP, SSRC, (const _Float16*)WF2,
                                  b2, w3_rel, w3_root, S, T, n);

  // layer 3
  k_final<<<(4 * n + B - 1) / B, B, 0, stream>>>(S, RP, SSRC, T, b3, (float*)d_out, n);
}

// Round 13
// 135.872 us; speedup vs baseline: 2.4564x; 1.0283x over previous
//
#include <hip/hip_runtime.h>
#include <hip/hip_fp16.h>

typedef _Float16 f16x8 __attribute__((ext_vector_type(8)));
typedef float    f32x4 __attribute__((ext_vector_type(4)));

constexpr int DIN = 32;
constexpr int DH  = 64;
constexpr int NBSHIFT = 8;            // 256 nodes per coarse bucket
constexpr int TILE_A  = 4096;         // edges per phase-A block
constexpr int FB_CAP  = 6144;         // fillB LDS sort capacity

// ===================== fused setup: x->fp16, weight frags, zero CH ==========

__global__ __launch_bounds__(256) void k_setup(
    const float2* __restrict__ x2, __half2* __restrict__ xh,
    const float* __restrict__ w1_rel, const float* __restrict__ w1_root,
    const float* __restrict__ w2_rel, const float* __restrict__ w2_root,
    __half* __restrict__ wf1, __half* __restrict__ wf2,
    int* __restrict__ ch, int n2) {
  int i = blockIdx.x * 256 + threadIdx.x;
  if (i < n2) {
    float2 v = x2[i];
    xh[i] = __floats2half2_rn(v.x, v.y);
    return;
  }
  int u = i - n2;
  if (u < 512) {                      // W1 A-frags: k<32 w1_root, k>=32 w1_rel
    int lane = u & 63, kt = (u >> 6) & 1, mt = u >> 7;
    int out = 16 * mt + (lane & 15);
    int kb = 32 * kt + (lane >> 4) * 8;
    union { uint4 q; __half h[8]; } pk;
#pragma unroll
    for (int j = 0; j < 8; ++j) {
      int k = kb + j;
      float w = (k < 32) ? w1_root[k * DH + out] : w1_rel[(k - 32) * DH + out];
      pk.h[j] = __float2half(w);
    }
    *(uint4*)(wf1 + (size_t)u * 8) = pk.q;
    return;
  }
  u -= 512;
  if (u < 1024) {                     // W2 A-frags: k<64 w2_rel, k>=64 w2_root
    int lane = u & 63, kt = (u >> 6) & 3, mt = u >> 8;
    int out = 16 * mt + (lane & 15);
    int kb = 32 * kt + (lane >> 4) * 8;
    union { uint4 q; __half h[8]; } pk;
#pragma unroll
    for (int j = 0; j < 8; ++j) {
      int k = kb + j;
      float w = (k < 64) ? w2_rel[k * DH + out] : w2_root[(k - 64) * DH + out];
      pk.h[j] = __float2half(w);
    }
    *(uint4*)(wf2 + (size_t)u * 8) = pk.q;
    return;
  }
  u -= 1024;
  if (u < 512) ch[u] = 0;
}

// ===================== CSR build =====================

__global__ __launch_bounds__(256) void k_chist(
    const int* __restrict__ dst, int* __restrict__ ch, int E, int nbuckets) {
  __shared__ int hist[512];
  long long t0 = (long long)blockIdx.x * TILE_A;
  int cnt = (int)min((long long)TILE_A, (long long)E - t0);
  for (int i = threadIdx.x; i < nbuckets; i += 256) hist[i] = 0;
  __syncthreads();
  for (int r = threadIdx.x; r < cnt; r += 256)
    atomicAdd(&hist[dst[t0 + r] >> NBSHIFT], 1);
  __syncthreads();
  for (int i = threadIdx.x; i < nbuckets; i += 256)
    if (hist[i]) atomicAdd(&ch[i], hist[i]);
}

__global__ __launch_bounds__(256) void k_cscan(
    const int* __restrict__ ch, int* __restrict__ cb, int* __restrict__ bcur,
    int nbuckets, int E) {
  __shared__ int ts[256];
  int i0 = threadIdx.x * 2, i1 = i0 + 1;
  int v0 = (i0 < nbuckets) ? ch[i0] : 0;
  int v1 = (i1 < nbuckets) ? ch[i1] : 0;
  int s = v0 + v1;
  ts[threadIdx.x] = s;
  __syncthreads();
  for (int off = 1; off < 256; off <<= 1) {
    int val = (threadIdx.x >= off) ? ts[threadIdx.x - off] : 0;
    __syncthreads();
    ts[threadIdx.x] += val;
    __syncthreads();
  }
  int ex = ts[threadIdx.x] - s;
  if (i0 < nbuckets) { cb[i0] = ex;      bcur[i0] = ex; }
  if (i1 < nbuckets) { cb[i1] = ex + v0; bcur[i1] = ex + v0; }
  if (threadIdx.x == 255) cb[nbuckets] = E;
}

// Phase A: bin edges into coarse buckets; LDS-sorted -> bucket-grouped writes.
__global__ __launch_bounds__(256) void k_binA(
    const int* __restrict__ src, const int* __restrict__ dst,
    int* __restrict__ bcur, unsigned* __restrict__ bin,
    int E, int nbuckets) {
  __shared__ int hist[512];
  __shared__ int lbase[512];
  __shared__ int gbase[512];
  __shared__ int ts[256];
  __shared__ unsigned lsort[TILE_A];
  __shared__ unsigned short lbuck[TILE_A];
  long long t0 = (long long)blockIdx.x * TILE_A;
  int cnt = (int)min((long long)TILE_A, (long long)E - t0);
  for (int i = threadIdx.x; i < 512; i += 256) hist[i] = 0;
  __syncthreads();
  unsigned pk[TILE_A / 256];
  int bo[TILE_A / 256];
#pragma unroll
  for (int q = 0; q < TILE_A / 256; ++q) {
    int r = (int)threadIdx.x + q * 256;
    if (r < cnt) {
      int d = dst[t0 + r];
      int s = src[t0 + r];
      int b = d >> NBSHIFT;
      int off = atomicAdd(&hist[b], 1);
      pk[q] = ((unsigned)(d & 255) << 17) | (unsigned)s;
      bo[q] = (b << 16) | off;
    }
  }
  __syncthreads();
  {
    int i0 = threadIdx.x * 2, i1 = i0 + 1;
    int v0 = hist[i0], v1 = hist[i1];
    int s2 = v0 + v1;
    ts[threadIdx.x] = s2;
    __syncthreads();
    for (int off = 1; off < 256; off <<= 1) {
      int val = (threadIdx.x >= off) ? ts[threadIdx.x - off] : 0;
      __syncthreads();
      ts[threadIdx.x] += val;
      __syncthreads();
    }
    int ex = ts[threadIdx.x] - s2;
    lbase[i0] = ex;
    lbase[i1] = ex + v0;
    gbase[i0] = v0 ? atomicAdd(&bcur[i0], v0) : 0;
    gbase[i1] = v1 ? atomicAdd(&bcur[i1], v1) : 0;
  }
  __syncthreads();
#pragma unroll
  for (int q = 0; q < TILE_A / 256; ++q) {
    int r = (int)threadIdx.x + q * 256;
    if (r < cnt) {
      int b = bo[q] >> 16, off = bo[q] & 0xFFFF;
      int li = lbase[b] + off;
      lsort[li] = pk[q];
      lbuck[li] = (unsigned short)b;
    }
  }
  __syncthreads();
  for (int i = threadIdx.x; i < cnt; i += 256) {
    int b = lbuck[i];
    bin[gbase[b] + (i - lbase[b])] = lsort[i];
  }
}

// Phase B: fine counting sort per bucket; coalesced ssrc writes via LDS.
__global__ __launch_bounds__(256) void k_fillB(
    const unsigned* __restrict__ bin, const int* __restrict__ cb,
    int* __restrict__ rp, int* __restrict__ ssrc, int n, int E) {
  __shared__ int deg[256];
  __shared__ int ts[256];
  __shared__ int cur[256];
  __shared__ int lsort[FB_CAP];
  int b = blockIdx.x;
  int nbase = b << NBSHIFT;
  int nn = min(256, n - nbase);
  int ebeg = cb[b], eend = cb[b + 1];
  int cnt = eend - ebeg;
  deg[threadIdx.x] = 0;
  __syncthreads();
  for (int e = ebeg + (int)threadIdx.x; e < eend; e += 256)
    atomicAdd(&deg[bin[e] >> 17], 1);
  __syncthreads();
  int d = deg[threadIdx.x];
  ts[threadIdx.x] = d;
  __syncthreads();
  for (int off = 1; off < 256; off <<= 1) {
    int val = (threadIdx.x >= off) ? ts[threadIdx.x - off] : 0;
    __syncthreads();
    ts[threadIdx.x] += val;
    __syncthreads();
  }
  int pref = ts[threadIdx.x] - d;
  if ((int)threadIdx.x < nn) rp[nbase + threadIdx.x] = ebeg + pref;
  if (b == 0 && threadIdx.x == 0) rp[n] = E;
  cur[threadIdx.x] = pref;
  __syncthreads();
  if (cnt <= FB_CAP) {
    for (int e = ebeg + (int)threadIdx.x; e < eend; e += 256) {
      unsigned u = bin[e];
      int pos = atomicAdd(&cur[u >> 17], 1);
      lsort[pos] = (int)(u & 0x1FFFF);
    }
    __syncthreads();
    for (int i = threadIdx.x; i < cnt; i += 256)
      ssrc[ebeg + i] = lsort[i];
  } else {
    for (int e = ebeg + (int)threadIdx.x; e < eend; e += 256) {
      unsigned u = bin[e];
      int pos = atomicAdd(&cur[u >> 17], 1);
      ssrc[ebeg + pos] = (int)(u & 0x1FFFF);
    }
  }
}

// ===================== layer 1 fused: gather(LDS) + MFMA =====================
// h1 = relu([x|agg1] @ [w1_root;w1_rel] + b1) -> fp16 H1[node][0..63]
// Gather: unroll 8 edges -> 8 independent 16B loads in flight per lane.
__global__ __launch_bounds__(256) void k_l1fused(
    const _Float16* __restrict__ X, const int* __restrict__ rp,
    const int* __restrict__ ssrc, const _Float16* __restrict__ WF,
    const float* __restrict__ b1, _Float16* __restrict__ H1, int n) {
  __shared__ _Float16 sagg[64][40];
  int tid = threadIdx.x;
  int nl = tid >> 2;
  int unit = tid & 3;
  int nodeg = blockIdx.x * 64 + nl;
  {
    f16x8 accA = (f16x8)(_Float16)0.0f;
    f16x8 accB = (f16x8)(_Float16)0.0f;
    if (nodeg < n) {
      int beg = rp[nodeg], end = rp[nodeg + 1];
      const f16x8* fx = (const f16x8*)X;
      int e = beg;
      for (; e + 7 < end; e += 8) {
        int s0 = ssrc[e],     s1 = ssrc[e + 1], s2 = ssrc[e + 2], s3 = ssrc[e + 3];
        int s4 = ssrc[e + 4], s5 = ssrc[e + 5], s6 = ssrc[e + 6], s7 = ssrc[e + 7];
        f16x8 v0 = fx[(size_t)s0 * 4 + unit];
        f16x8 v1 = fx[(size_t)s1 * 4 + unit];
        f16x8 v2 = fx[(size_t)s2 * 4 + unit];
        f16x8 v3 = fx[(size_t)s3 * 4 + unit];
        f16x8 v4 = fx[(size_t)s4 * 4 + unit];
        f16x8 v5 = fx[(size_t)s5 * 4 + unit];
        f16x8 v6 = fx[(size_t)s6 * 4 + unit];
        f16x8 v7 = fx[(size_t)s7 * 4 + unit];
        accA += v0; accB += v1; accA += v2; accB += v3;
        accA += v4; accB += v5; accA += v6; accB += v7;
      }
      for (; e + 1 < end; e += 2) {
        int s0 = ssrc[e], s1 = ssrc[e + 1];
        f16x8 v0 = fx[(size_t)s0 * 4 + unit];
        f16x8 v1 = fx[(size_t)s1 * 4 + unit];
        accA += v0; accB += v1;
      }
      if (e < end) accA += fx[(size_t)ssrc[e] * 4 + unit];
    }
    *(f16x8*)&sagg[nl][unit * 8] = accA + accB;
  }
  __syncthreads();
  int lane = tid & 63;
  int w = tid >> 6;
  int nl16 = w * 16 + (lane & 15);
  int node = blockIdx.x * 64 + nl16;
  int nodeld = min(node, n - 1);
  f16x8 bf0 = *(const f16x8*)(X + (size_t)nodeld * 32 + (lane >> 4) * 8);
  f16x8 bf1 = *(const f16x8*)&sagg[nl16][(lane >> 4) * 8];
  const f16x8* ap = (const f16x8*)WF + lane;
  f32x4 acc[4];
#pragma unroll
  for (int mt = 0; mt < 4; ++mt) acc[mt] = (f32x4)(0.f);
#pragma unroll
  for (int mt = 0; mt < 4; ++mt) {
    acc[mt] = __builtin_amdgcn_mfma_f32_16x16x32_f16(ap[(mt * 2 + 0) * 64], bf0, acc[mt], 0, 0, 0);
    acc[mt] = __builtin_amdgcn_mfma_f32_16x16x32_f16(ap[(mt * 2 + 1) * 64], bf1, acc[mt], 0, 0, 0);
  }
  if (node >= n) return;
  int jb = (lane >> 4) * 4;
  _Float16* op = H1 + (size_t)node * 64 + jb;
#pragma unroll
  for (int mt = 0; mt < 4; ++mt) {
    f32x4 vb = *(const f32x4*)(b1 + 16 * mt + jb);
    union { uint2 u2; _Float16 h[4]; } pko;
#pragma unroll
    for (int r = 0; r < 4; ++r)
      pko.h[r] = (_Float16)fmaxf(acc[mt][r] + vb[r], 0.f);
    *(uint2*)(op + 16 * mt) = pko.u2;
  }
}

// ===================== layer 2 fused: gather(LDS) + MFMA + proj =============
// h2 = relu([agg2|h1] @ [w2_rel;w2_root] + b2); S=h2@w3_rel, T=h2@w3_root
// Gather: unroll 8 edges x 2 units -> 16 independent 16B loads in flight.
__global__ __launch_bounds__(256) void k_l2fused(
    const _Float16* __restrict__ H1, const int* __restrict__ rp,
    const int* __restrict__ ssrc, const _Float16* __restrict__ WF,
    const float* __restrict__ b2, const float* __restrict__ w3rel,
    const float* __restrict__ w3root,
    float* __restrict__ S, float* __restrict__ T, int n) {
  __shared__ _Float16 sagg[64][72];
  int tid = threadIdx.x;
  int nl = tid >> 2;
  int u0 = tid & 3;                   // lane covers units u0 and u0+4
  int nodeg = blockIdx.x * 64 + nl;
  {
    f16x8 aA = (f16x8)(_Float16)0.0f, aB = (f16x8)(_Float16)0.0f;
    f16x8 cA = (f16x8)(_Float16)0.0f, cB = (f16x8)(_Float16)0.0f;
    if (nodeg < n) {
      int beg = rp[nodeg], end = rp[nodeg + 1];
      const f16x8* fh = (const f16x8*)H1;
      int e = beg;
      for (; e + 7 < end; e += 8) {
        int s0 = ssrc[e],     s1 = ssrc[e + 1], s2 = ssrc[e + 2], s3 = ssrc[e + 3];
        int s4 = ssrc[e + 4], s5 = ssrc[e + 5], s6 = ssrc[e + 6], s7 = ssrc[e + 7];
        f16x8 a0 = fh[(size_t)s0 * 8 + u0];
        f16x8 c0 = fh[(size_t)s0 * 8 + u0 + 4];
        f16x8 a1 = fh[(size_t)s1 * 8 + u0];
        f16x8 c1 = fh[(size_t)s1 * 8 + u0 + 4];
        f16x8 a2 = fh[(size_t)s2 * 8 + u0];
        f16x8 c2 = fh[(size_t)s2 * 8 + u0 + 4];
        f16x8 a3 = fh[(size_t)s3 * 8 + u0];
        f16x8 c3 = fh[(size_t)s3 * 8 + u0 + 4];
        f16x8 a4 = fh[(size_t)s4 * 8 + u0];
        f16x8 c4 = fh[(size_t)s4 * 8 + u0 + 4];
        f16x8 a5 = fh[(size_t)s5 * 8 + u0];
        f16x8 c5 = fh[(size_t)s5 * 8 + u0 + 4];
        f16x8 a6 = fh[(size_t)s6 * 8 + u0];
        f16x8 c6 = fh[(size_t)s6 * 8 + u0 + 4];
        f16x8 a7 = fh[(size_t)s7 * 8 + u0];
        f16x8 c7 = fh[(size_t)s7 * 8 + u0 + 4];
        aA += a0; cA += c0; aB += a1; cB += c1;
        aA += a2; cA += c2; aB += a3; cB += c3;
        aA += a4; cA += c4; aB += a5; cB += c5;
        aA += a6; cA += c6; aB += a7; cB += c7;
      }
      for (; e + 1 < end; e += 2) {
        int s0 = ssrc[e], s1 = ssrc[e + 1];
        aA += fh[(size_t)s0 * 8 + u0];
        cA += fh[(size_t)s0 * 8 + u0 + 4];
        aB += fh[(size_t)s1 * 8 + u0];
        cB += fh[(size_t)s1 * 8 + u0 + 4];
      }
      if (e < end) {
        int s0 = ssrc[e];
        aA += fh[(size_t)s0 * 8 + u0];
        cA += fh[(size_t)s0 * 8 + u0 + 4];
      }
    }
    *(f16x8*)&sagg[nl][u0 * 8] = aA + aB;
    *(f16x8*)&sagg[nl][(u0 + 4) * 8] = cA + cB;
  }
  __syncthreads();
  int lane = tid & 63;
  int w = tid >> 6;
  int nl16 = w * 16 + (lane & 15);
  int node = blockIdx.x * 64 + nl16;
  int nodeld = min(node, n - 1);
  f16x8 bf[4];
  bf[0] = *(const f16x8*)&sagg[nl16][(lane >> 4) * 8];
  bf[1] = *(const f16x8*)&sagg[nl16][32 + (lane >> 4) * 8];
  bf[2] = *(const f16x8*)(H1 + (size_t)nodeld * 64 + (lane >> 4) * 8);
  bf[3] = *(const f16x8*)(H1 + (size_t)nodeld * 64 + 32 + (lane >> 4) * 8);
  const f16x8* ap = (const f16x8*)WF + lane;
  f32x4 acc[4];
#pragma unroll
  for (int mt = 0; mt < 4; ++mt) acc[mt] = (f32x4)(0.f);
#pragma unroll
  for (int mt = 0; mt < 4; ++mt)
#pragma unroll
    for (int kt = 0; kt < 4; ++kt)
      acc[mt] = __builtin_amdgcn_mfma_f32_16x16x32_f16(
          ap[(mt * 4 + kt) * 64], bf[kt], acc[mt], 0, 0, 0);
  int jb = (lane >> 4) * 4;
  float s = 0.f, t = 0.f;
#pragma unroll
  for (int mt = 0; mt < 4; ++mt) {
    f32x4 vb = *(const f32x4*)(b2 + 16 * mt + jb);
    f32x4 vr = *(const f32x4*)(w3rel + 16 * mt + jb);
    f32x4 vt = *(const f32x4*)(w3root + 16 * mt + jb);
#pragma unroll
    for (int r = 0; r < 4; ++r) {
      float h = fmaxf(acc[mt][r] + vb[r], 0.f);
      s = fmaf(h, vr[r], s);
      t = fmaf(h, vt[r], t);
    }
  }
  s += __shfl_xor(s, 16); s += __shfl_xor(s, 32);
  t += __shfl_xor(t, 16); t += __shfl_xor(t, 32);
  if (lane < 16 && node < n) { S[node] = s; T[node] = t; }
}

// ===================== final: out = segsum(S) + b3 + T (4 lanes/node) =======

__global__ __launch_bounds__(256) void k_final(
    const float* __restrict__ sv, const int* __restrict__ rp,
    const int* __restrict__ ssrc, const float* __restrict__ T,
    const float* __restrict__ b3, float* __restrict__ out, int n) {
  int t = blockIdx.x * 256 + threadIdx.x;
  int node = t >> 2;
  int l = t & 3;
  if (node >= n) return;
  int beg = rp[node], end = rp[node + 1];
  float a = 0.f;
  for (int e = beg + l; e < end; e += 4) a += sv[ssrc[e]];
  a += __shfl_xor(a, 1);
  a += __shfl_xor(a, 2);
  if (l == 0) out[node] = a + b3[0] + T[node];
}

// ===================== launch =====================

extern "C" void kernel_launch(void* const* d_in, const int* in_sizes, int n_in,
                              void* d_out, int out_size, void* d_ws, size_t ws_size,
                              hipStream_t stream) {
  const float* x       = (const float*)d_in[0];
  const float* w1_rel  = (const float*)d_in[1];
  const float* b1      = (const float*)d_in[2];
  const float* w1_root = (const float*)d_in[3];
  const float* w2_rel  = (const float*)d_in[4];
  const float* b2      = (const float*)d_in[5];
  const float* w2_root = (const float*)d_in[6];
  const float* w3_rel  = (const float*)d_in[7];
  const float* b3      = (const float*)d_in[8];
  const float* w3_root = (const float*)d_in[9];
  const int*   edge    = (const int*)d_in[10];

  const int n = in_sizes[0] / DIN;        // 100000 (< 2^17 for packing)
  const int E = in_sizes[10] / 2;         // 1600000
  const int* src = edge;
  const int* dst = edge + E;

  _Float16* XH = (_Float16*)d_ws;                     // n*32 halfs (x fp16)
  _Float16* H1 = XH + (size_t)n * 32;                 // n*64 halfs (h1)
  float*    S  = (float*)(H1 + (size_t)n * 64);       // n
  float*    T  = S + n;                               // n
  int* RP   = (int*)(T + n);                          // n+1 (pad to 8)
  int* SSRC = RP + ((n + 8) & ~7);                    // E
  int* CH   = SSRC + E;                               // 512
  int* CB   = CH + 512;                               // 513 (pad 520)
  int* BCUR = CB + 520;                               // 512
  __half* WF1 = (__half*)(BCUR + 512);                // 4096 halfs
  __half* WF2 = WF1 + 4096;                           // 8192 halfs
  unsigned* BIN = (unsigned*)H1;                      // E (dead before H1 writes)

  const int B = 256;
  const int nbuckets = (n + 255) >> NBSHIFT;          // 391
  const int gA = (E + TILE_A - 1) / TILE_A;           // 391
  const int gF = (n + 63) / 64;                       // fused-layer blocks

  // setup: x->fp16 | W1 frags | W2 frags | zero CH
  {
    int n2 = n * 16;
    int tot = n2 + 2048;
    k_setup<<<(tot + B - 1) / B, B, 0, stream>>>(
        (const float2*)x, (__half2*)XH, w1_rel, w1_root, w2_rel, w2_root,
        WF1, WF2, CH, n2);
  }

  // CSR build
  k_chist<<<gA, B, 0, stream>>>(dst, CH, E, nbuckets);
  k_cscan<<<1, B, 0, stream>>>(CH, CB, BCUR, nbuckets, E);
  k_binA<<<gA, B, 0, stream>>>(src, dst, BCUR, BIN, E, nbuckets);
  k_fillB<<<nbuckets, B, 0, stream>>>(BIN, CB, RP, SSRC, n, E);

  // layers (gather fused with MFMA; agg in LDS, packed-fp16 accumulate)
  k_l1fused<<<gF, B, 0, stream>>>(XH, RP, SSRC, (const _Float16*)WF1, b1, H1, n);
  k_l2fused<<<gF, B, 0, stream>>>(H1, RP, SSRC, (const _Float16*)WF2,
                                  b2, w3_rel, w3_root, S, T, n);

  // layer 3
  k_final<<<(4 * n + B - 1) / B, B, 0, stream>>>(S, RP, SSRC, T, b3, (float*)d_out, n);
}